// Round 1
// baseline (527.504 us; speedup 1.0000x reference)
//
#include <hip/hip_runtime.h>

typedef unsigned short u16;
typedef __bf16 bf16x8 __attribute__((ext_vector_type(8)));
typedef float f32x4 __attribute__((ext_vector_type(4)));

#define NROW 8192
#define CAP 128
#define D_IN 512
#define D_HID 256
#define D_OUT 128

__device__ __forceinline__ float leaky_f(float x) { return x > 0.f ? x : 0.25f * x; }

__device__ __forceinline__ u16 f2bf_rne(float f) {
  unsigned u = __float_as_uint(f);
  u += 0x7fffu + ((u >> 16) & 1u);
  return (u16)(u >> 16);
}
__device__ __forceinline__ void split_bf16(float f, u16& hi, u16& lo) {
  hi = f2bf_rne(f);
  float fh = __uint_as_float(((unsigned)hi) << 16);
  lo = f2bf_rne(f - fh);
}

// ---------------- CSR build: adj (8192x8192 fp32) -> per-row (cols, vals, cnt) ----------------
__global__ __launch_bounds__(256) void k_csr(const float* __restrict__ adj,
    int* __restrict__ cnt, int* __restrict__ cols, float* __restrict__ vals) {
  int i = blockIdx.x;
  __shared__ int c;
  if (threadIdx.x == 0) c = 0;
  __syncthreads();
  const float4* row = (const float4*)(adj + (size_t)i * NROW);
  for (int j4 = threadIdx.x; j4 < NROW / 4; j4 += 256) {
    float4 v = row[j4];
    int base = j4 * 4;
    if (v.x > 0.f) { int s = atomicAdd(&c, 1); if (s < CAP) { cols[i*CAP+s] = base;   vals[i*CAP+s] = v.x; } }
    if (v.y > 0.f) { int s = atomicAdd(&c, 1); if (s < CAP) { cols[i*CAP+s] = base+1; vals[i*CAP+s] = v.y; } }
    if (v.z > 0.f) { int s = atomicAdd(&c, 1); if (s < CAP) { cols[i*CAP+s] = base+2; vals[i*CAP+s] = v.z; } }
    if (v.w > 0.f) { int s = atomicAdd(&c, 1); if (s < CAP) { cols[i*CAP+s] = base+3; vals[i*CAP+s] = v.w; } }
  }
  __syncthreads();
  if (threadIdx.x == 0) cnt[i] = (c < CAP) ? c : CAP;
}

// ---------------- pack A (x -> [hi|hi|lo] bf16, K=512 -> 1536) ----------------
__global__ __launch_bounds__(256) void k_pack_x(const float* __restrict__ X, u16* __restrict__ Ap) {
  size_t id = (size_t)blockIdx.x * 256 + threadIdx.x;   // M*K threads, K=512
  int k = (int)(id & 511);
  size_t i = id >> 9;
  float f = X[id];
  u16 hi, lo; split_bf16(f, hi, lo);
  size_t ro = i * 1536;
  Ap[ro + k] = hi; Ap[ro + 512 + k] = hi; Ap[ro + 1024 + k] = lo;
}

// ---------------- pack W (K x Nc fp32) -> Bt (Nc x 3K bf16, rows [hi|lo|hi]) ----------------
__global__ __launch_bounds__(256) void k_pack_w(const float* __restrict__ W, u16* __restrict__ Bt,
                                                int K, int Nc) {
  int id = blockIdx.x * 256 + threadIdx.x;
  if (id >= K * Nc) return;
  int n = id % Nc, k = id / Nc;
  float f = W[id];
  u16 hi, lo; split_bf16(f, hi, lo);
  size_t ro = (size_t)n * 3 * K;
  Bt[ro + k] = hi; Bt[ro + K + k] = lo; Bt[ro + 2*K + k] = hi;
}

// ---------------- GEMM: C[M][N] = A[M][K] @ Bt[N][K]^T  (bf16 in, fp32 out) ----------------
// block 256 = 4 waves; tile 64x64; K-step 32; wave w computes rows [16w,16w+16) x 64 cols
__global__ __launch_bounds__(256) void k_gemm(const u16* __restrict__ A, const u16* __restrict__ Bt,
    float* __restrict__ C, int N, int K) {
  __shared__ u16 As[64][40];   // +8 pad: 2-way max bank aliasing on b128 reads
  __shared__ u16 Bs[64][40];
  int tid = threadIdx.x;
  int bm = blockIdx.y * 64, bn = blockIdx.x * 64;
  int wave = tid >> 6, lane = tid & 63, l15 = lane & 15, quad = lane >> 4;
  f32x4 acc[4] = {};
  int r = tid >> 2, kc = (tid & 3) << 3;
  for (int k0 = 0; k0 < K; k0 += 32) {
    uint4 av = *(const uint4*)(A + (size_t)(bm + r) * K + k0 + kc);
    uint4 bv = *(const uint4*)(Bt + (size_t)(bn + r) * K + k0 + kc);
    *(uint4*)(&As[r][kc]) = av;
    *(uint4*)(&Bs[r][kc]) = bv;
    __syncthreads();
    bf16x8 af = *(const bf16x8*)(&As[wave * 16 + l15][quad * 8]);
#pragma unroll
    for (int c2 = 0; c2 < 4; ++c2) {
      bf16x8 bfr = *(const bf16x8*)(&Bs[c2 * 16 + l15][quad * 8]);
      acc[c2] = __builtin_amdgcn_mfma_f32_16x16x32_bf16(af, bfr, acc[c2], 0, 0, 0);
    }
    __syncthreads();
  }
#pragma unroll
  for (int c2 = 0; c2 < 4; ++c2)
#pragma unroll
    for (int rg = 0; rg < 4; ++rg) {
      int rowi = bm + wave * 16 + quad * 4 + rg;   // C/D: col=lane&15, row=quad*4+reg
      int coli = bn + c2 * 16 + l15;
      C[(size_t)rowi * N + coli] = acc[c2][rg];
    }
}

// ---------------- SpMM + bias + leaky + split-pack: Ap[i] = pack(leaky(adj_row_i @ Hin + b)) ----------------
__global__ __launch_bounds__(256) void k_spmm_pack(const float* __restrict__ Hin,
    const float* __restrict__ bias, const int* __restrict__ cnt,
    const int* __restrict__ cols, const float* __restrict__ vals, u16* __restrict__ Ap) {
  int i = blockIdx.x, t = threadIdx.x;
  __shared__ int sc[CAP];
  __shared__ float sv[CAP];
  int n = cnt[i];
  if (t < n) { sc[t] = cols[i * CAP + t]; sv[t] = vals[i * CAP + t]; }
  __syncthreads();
  float acc = bias[t];
  for (int k = 0; k < n; ++k)
    acc = fmaf(sv[k], Hin[(size_t)sc[k] * D_HID + t], acc);
  acc = leaky_f(acc);
  u16 hi, lo; split_bf16(acc, hi, lo);
  size_t ro = (size_t)i * 768;
  Ap[ro + t] = hi; Ap[ro + 256 + t] = hi; Ap[ro + 512 + t] = lo;
}

// ---------------- s1 = h@a1, s2 = h@a2 ----------------
__global__ __launch_bounds__(64) void k_sdot(const float* __restrict__ h,
    const float* __restrict__ a, float* __restrict__ s1, float* __restrict__ s2) {
  int i = blockIdx.x, t = threadIdx.x;
  float v0 = h[(size_t)i * D_OUT + t], v1 = h[(size_t)i * D_OUT + 64 + t];
  float p1 = v0 * a[t] + v1 * a[64 + t];
  float p2 = v0 * a[128 + t] + v1 * a[192 + t];
  for (int o = 32; o > 0; o >>= 1) { p1 += __shfl_down(p1, o); p2 += __shfl_down(p2, o); }
  if (t == 0) { s1[i] = p1; s2[i] = p2; }
}

// ---------------- attention: softmax over neighbors + aggregate + leaky + mu/logvar split ----------------
__global__ __launch_bounds__(128) void k_attn(const float* __restrict__ h,
    const float* __restrict__ s1, const float* __restrict__ s2,
    const int* __restrict__ cnt, const int* __restrict__ cols, float* __restrict__ out) {
  int i = blockIdx.x, t = threadIdx.x;
  __shared__ int sc[CAP];
  __shared__ float sw[CAP];
  __shared__ float sred[2];
  int n = cnt[i];
  float s1i = s1[i];
  if (t < n) { int c = cols[i * CAP + t]; sc[t] = c; sw[t] = leaky_f(s1i + s2[c]); }
  __syncthreads();
  if (t < 64) {  // wave 0: max reduce
    float m = -1e30f;
    if (t < n) m = sw[t];
    if (t + 64 < n) m = fmaxf(m, sw[t + 64]);
    for (int o = 32; o > 0; o >>= 1) m = fmaxf(m, __shfl_down(m, o));
    if (t == 0) sred[0] = m;
  }
  __syncthreads();
  float mx = sred[0];
  if (t < n) sw[t] = expf(sw[t] - mx);
  __syncthreads();
  if (t < 64) {  // wave 0: sum reduce
    float s = 0.f;
    if (t < n) s = sw[t];
    if (t + 64 < n) s += sw[t + 64];
    for (int o = 32; o > 0; o >>= 1) s += __shfl_down(s, o);
    if (t == 0) sred[1] = s;
  }
  __syncthreads();
  float inv = (n > 0) ? 1.0f / sred[1] : 0.f;
  float acc = 0.f;
  for (int k = 0; k < n; ++k)
    acc = fmaf(sw[k], h[(size_t)sc[k] * D_OUT + t], acc);
  acc = leaky_f(acc * inv);
  // out tuple: mu = out[:, :64] flat first, then logvar = out[:, 64:]
  if (t < 64) out[(size_t)i * 64 + t] = acc;
  else        out[(size_t)NROW * 64 + (size_t)i * 64 + (t - 64)] = acc;
}

extern "C" void kernel_launch(void* const* d_in, const int* in_sizes, int n_in,
                              void* d_out, int out_size, void* d_ws, size_t ws_size,
                              hipStream_t stream) {
  const float* x   = (const float*)d_in[0];
  const float* adj = (const float*)d_in[1];
  const float* W1  = (const float*)d_in[2];
  const float* b1  = (const float*)d_in[3];
  const float* W2  = (const float*)d_in[4];
  const float* b2  = (const float*)d_in[5];
  const float* Wg  = (const float*)d_in[6];
  const float* a   = (const float*)d_in[7];
  float* out = (float*)d_out;

  char* ws = (char*)d_ws;
  int*   row_cnt  = (int*)  (ws + 0);          //   32 KB
  int*   row_cols = (int*)  (ws + 32768);      // 4 MB
  float* row_vals = (float*)(ws + 4227072);    // 4 MB
  u16*   B1t      = (u16*)  (ws + 8421376);    // 768 KB (256 x 1536)
  u16*   B2t      = (u16*)  (ws + 9207808);    // 384 KB (256 x 768)
  u16*   B3t      = (u16*)  (ws + 9601024);    // 192 KB (128 x 768)
  float* s1       = (float*)(ws + 9797632);    //  32 KB
  float* s2       = (float*)(ws + 9830400);    //  32 KB
  float* h        = (float*)(ws + 9863168);    // 4 MB (8192 x 128)
  float* H0T2     = (float*)(ws + 14057472);   // 8 MB (8192 x 256), reused for T2
  u16*   Apack    = (u16*)  (ws + 22446080);   // 25.2 MB (8192 x 1536), reused A1/A2/A3
  // total ws usage: ~47.6 MB

  // 1. CSR build (reads adj once — the 268 MB structural floor)
  k_csr<<<NROW, 256, 0, stream>>>(adj, row_cnt, row_cols, row_vals);
  // 2. pack inputs/weights to split-bf16
  k_pack_x<<<(NROW * D_IN) / 256, 256, 0, stream>>>(x, Apack);
  k_pack_w<<<(D_IN * D_HID + 255) / 256, 256, 0, stream>>>(W1, B1t, D_IN, D_HID);
  k_pack_w<<<(D_HID * D_HID + 255) / 256, 256, 0, stream>>>(W2, B2t, D_HID, D_HID);
  k_pack_w<<<(D_HID * D_OUT + 255) / 256, 256, 0, stream>>>(Wg, B3t, D_HID, D_OUT);
  // 3. H0 = x @ W1   (split-bf16, K'=1536)
  k_gemm<<<dim3(D_HID / 64, NROW / 64), 256, 0, stream>>>(Apack, B1t, H0T2, D_HID, 3 * D_IN);
  // 4. x1 = leaky(adj @ H0 + b1) -> packed A2
  k_spmm_pack<<<NROW, 256, 0, stream>>>(H0T2, b1, row_cnt, row_cols, row_vals, Apack);
  // 5. T2 = x1 @ W2  (K'=768)
  k_gemm<<<dim3(D_HID / 64, NROW / 64), 256, 0, stream>>>(Apack, B2t, H0T2, D_HID, 3 * D_HID);
  // 6. x2 = leaky(adj @ T2 + b2) -> packed A3
  k_spmm_pack<<<NROW, 256, 0, stream>>>(H0T2, b2, row_cnt, row_cols, row_vals, Apack);
  // 7. h = x2 @ Wg   (K'=768, N=128)
  k_gemm<<<dim3(D_OUT / 64, NROW / 64), 256, 0, stream>>>(Apack, B3t, h, D_OUT, 3 * D_HID);
  // 8. s1/s2 logit projections
  k_sdot<<<NROW, 64, 0, stream>>>(h, a, s1, s2);
  // 9. masked softmax attention + aggregate + output split
  k_attn<<<NROW, 128, 0, stream>>>(h, s1, s2, row_cnt, row_cols, out);
}

// Round 2
// 517.892 us; speedup vs baseline: 1.0186x; 1.0186x over previous
//
#include <hip/hip_runtime.h>

typedef unsigned short u16;
typedef __bf16 bf16x8 __attribute__((ext_vector_type(8)));
typedef float f32x4 __attribute__((ext_vector_type(4)));

#define NROW 8192
#define CAP 128
#define D_IN 512
#define D_HID 256
#define D_OUT 128

__device__ __forceinline__ float leaky_f(float x) { return x > 0.f ? x : 0.25f * x; }

__device__ __forceinline__ u16 f2bf_rne(float f) {
  unsigned u = __float_as_uint(f);
  u += 0x7fffu + ((u >> 16) & 1u);
  return (u16)(u >> 16);
}
__device__ __forceinline__ void split_bf16(float f, u16& hi, u16& lo) {
  hi = f2bf_rne(f);
  float fh = __uint_as_float(((unsigned)hi) << 16);
  lo = f2bf_rne(f - fh);
}

// ---------------- CSR build: adj (8192x8192 fp32) -> per-row (cols, vals, cnt) ----------------
__global__ __launch_bounds__(256) void k_csr(const float* __restrict__ adj,
    int* __restrict__ cnt, int* __restrict__ cols, float* __restrict__ vals) {
  int i = blockIdx.x;
  __shared__ int c;
  if (threadIdx.x == 0) c = 0;
  __syncthreads();
  const float4* row = (const float4*)(adj + (size_t)i * NROW);
  for (int j4 = threadIdx.x; j4 < NROW / 4; j4 += 256) {
    float4 v = row[j4];
    int base = j4 * 4;
    if (v.x > 0.f) { int s = atomicAdd(&c, 1); if (s < CAP) { cols[i*CAP+s] = base;   vals[i*CAP+s] = v.x; } }
    if (v.y > 0.f) { int s = atomicAdd(&c, 1); if (s < CAP) { cols[i*CAP+s] = base+1; vals[i*CAP+s] = v.y; } }
    if (v.z > 0.f) { int s = atomicAdd(&c, 1); if (s < CAP) { cols[i*CAP+s] = base+2; vals[i*CAP+s] = v.z; } }
    if (v.w > 0.f) { int s = atomicAdd(&c, 1); if (s < CAP) { cols[i*CAP+s] = base+3; vals[i*CAP+s] = v.w; } }
  }
  __syncthreads();
  if (threadIdx.x == 0) cnt[i] = (c < CAP) ? c : CAP;
}

// ---------------- fused pack: x -> Apack (tripled-K), W1/W2/Wg -> B*t (transposed tripled-K) ----------------
// block regions: [0,16384) x | [16384,16896) W1 | [16896,17152) W2 | [17152,17280) Wg
__global__ __launch_bounds__(256) void k_pack_all(const float* __restrict__ X, u16* __restrict__ Ap,
    const float* __restrict__ W1, u16* __restrict__ B1,
    const float* __restrict__ W2, u16* __restrict__ B2,
    const float* __restrict__ Wg, u16* __restrict__ B3) {
  int b = blockIdx.x;
  if (b < 16384) {
    size_t id = (size_t)b * 256 + threadIdx.x;   // N*D_IN threads
    int k = (int)(id & 511);
    size_t i = id >> 9;
    float f = X[id];
    u16 hi, lo; split_bf16(f, hi, lo);
    size_t ro = i * 1536;
    Ap[ro + k] = hi; Ap[ro + 512 + k] = hi; Ap[ro + 1024 + k] = lo;
    return;
  }
  const float* W; u16* Bt; int K, Nc, id;
  if (b < 16896)      { W = W1; Bt = B1; K = D_IN;  Nc = D_HID; id = (b - 16384) * 256 + threadIdx.x; }
  else if (b < 17152) { W = W2; Bt = B2; K = D_HID; Nc = D_HID; id = (b - 16896) * 256 + threadIdx.x; }
  else                { W = Wg; Bt = B3; K = D_HID; Nc = D_OUT; id = (b - 17152) * 256 + threadIdx.x; }
  if (id >= K * Nc) return;
  int n = id % Nc, k = id / Nc;
  float f = W[id];
  u16 hi, lo; split_bf16(f, hi, lo);
  size_t ro = (size_t)n * 3 * K;
  Bt[ro + k] = hi; Bt[ro + K + k] = lo; Bt[ro + 2*K + k] = hi;
}

// ---------------- GEMM: C[M][N] = A[M][K] @ Bt[N][K]^T  (bf16 in, fp32 out) ----------------
// m93-class: tile 128x64, BK=64, 4 waves, wave w -> rows [32w,32w+32) x 64 cols.
// LDS rows padded to 72 u16 (144 B): bank group rotates 4*((l15+q)%8) -> conflict-light b128 reads.
__global__ __launch_bounds__(256) void k_gemm(const u16* __restrict__ A, const u16* __restrict__ Bt,
    float* __restrict__ C, int N, int K) {
  __shared__ u16 As[128 * 72];   // 18 KB
  __shared__ u16 Bs[64 * 72];    //  9 KB
  int tid = threadIdx.x;
  int bm = blockIdx.y * 128, bn = blockIdx.x * 64;
  int wave = tid >> 6, lane = tid & 63, l15 = lane & 15, quad = lane >> 4;
  f32x4 acc[2][4] = {};
  // staging maps (uint4 = 8 u16)
  int ar = tid >> 1, ac = (tid & 1) * 32;      // A: 128 rows, this thread: row ar, u16 cols [ac,ac+32)
  int br = tid >> 2, bc = (tid & 3) * 16;      // B: 64 rows,  this thread: row br, u16 cols [bc,bc+16)
  const u16* Arow = A + (size_t)(bm + ar) * K + ac;
  const u16* Brow = Bt + (size_t)(bn + br) * K + bc;
  for (int k0 = 0; k0 < K; k0 += 64) {
#pragma unroll
    for (int j = 0; j < 4; ++j)
      *(uint4*)(&As[ar * 72 + ac + j * 8]) = *(const uint4*)(Arow + k0 + j * 8);
#pragma unroll
    for (int j = 0; j < 2; ++j)
      *(uint4*)(&Bs[br * 72 + bc + j * 8]) = *(const uint4*)(Brow + k0 + j * 8);
    __syncthreads();
#pragma unroll
    for (int kk = 0; kk < 64; kk += 32) {
      bf16x8 af[2], bf[4];
#pragma unroll
      for (int r = 0; r < 2; ++r)
        af[r] = *(const bf16x8*)(&As[(wave * 32 + r * 16 + l15) * 72 + kk + quad * 8]);
#pragma unroll
      for (int c = 0; c < 4; ++c)
        bf[c] = *(const bf16x8*)(&Bs[(c * 16 + l15) * 72 + kk + quad * 8]);
#pragma unroll
      for (int r = 0; r < 2; ++r)
#pragma unroll
        for (int c = 0; c < 4; ++c)
          acc[r][c] = __builtin_amdgcn_mfma_f32_16x16x32_bf16(af[r], bf[c], acc[r][c], 0, 0, 0);
    }
    __syncthreads();
  }
#pragma unroll
  for (int r = 0; r < 2; ++r)
#pragma unroll
    for (int c = 0; c < 4; ++c)
#pragma unroll
      for (int rg = 0; rg < 4; ++rg) {
        int rowi = bm + wave * 32 + r * 16 + quad * 4 + rg;  // C/D: col=lane&15, row=quad*4+reg
        int coli = bn + c * 16 + l15;
        C[(size_t)rowi * N + coli] = acc[r][c][rg];
      }
}

// ---------------- SpMM + bias + leaky + split-pack: Ap[i] = pack(leaky(adj_row_i @ Hin + b)) ----------------
__global__ __launch_bounds__(256) void k_spmm_pack(const float* __restrict__ Hin,
    const float* __restrict__ bias, const int* __restrict__ cnt,
    const int* __restrict__ cols, const float* __restrict__ vals, u16* __restrict__ Ap) {
  int i = blockIdx.x, t = threadIdx.x;
  __shared__ int sc[CAP];
  __shared__ float sv[CAP];
  int n = cnt[i];
  if (t < n) { sc[t] = cols[i * CAP + t]; sv[t] = vals[i * CAP + t]; }
  __syncthreads();
  float acc = bias[t];
  for (int k = 0; k < n; ++k)
    acc = fmaf(sv[k], Hin[(size_t)sc[k] * D_HID + t], acc);
  acc = leaky_f(acc);
  u16 hi, lo; split_bf16(acc, hi, lo);
  size_t ro = (size_t)i * 768;
  Ap[ro + t] = hi; Ap[ro + 256 + t] = hi; Ap[ro + 512 + t] = lo;
}

// ---------------- s1 = h@a1, s2 = h@a2 ----------------
__global__ __launch_bounds__(64) void k_sdot(const float* __restrict__ h,
    const float* __restrict__ a, float* __restrict__ s1, float* __restrict__ s2) {
  int i = blockIdx.x, t = threadIdx.x;
  float v0 = h[(size_t)i * D_OUT + t], v1 = h[(size_t)i * D_OUT + 64 + t];
  float p1 = v0 * a[t] + v1 * a[64 + t];
  float p2 = v0 * a[128 + t] + v1 * a[192 + t];
  for (int o = 32; o > 0; o >>= 1) { p1 += __shfl_down(p1, o); p2 += __shfl_down(p2, o); }
  if (t == 0) { s1[i] = p1; s2[i] = p2; }
}

// ---------------- attention: softmax over neighbors + aggregate + leaky + mu/logvar split ----------------
__global__ __launch_bounds__(128) void k_attn(const float* __restrict__ h,
    const float* __restrict__ s1, const float* __restrict__ s2,
    const int* __restrict__ cnt, const int* __restrict__ cols, float* __restrict__ out) {
  int i = blockIdx.x, t = threadIdx.x;
  __shared__ int sc[CAP];
  __shared__ float sw[CAP];
  __shared__ float sred[2];
  int n = cnt[i];
  float s1i = s1[i];
  if (t < n) { int c = cols[i * CAP + t]; sc[t] = c; sw[t] = leaky_f(s1i + s2[c]); }
  __syncthreads();
  if (t < 64) {  // wave 0: max reduce
    float m = -1e30f;
    if (t < n) m = sw[t];
    if (t + 64 < n) m = fmaxf(m, sw[t + 64]);
    for (int o = 32; o > 0; o >>= 1) m = fmaxf(m, __shfl_down(m, o));
    if (t == 0) sred[0] = m;
  }
  __syncthreads();
  float mx = sred[0];
  if (t < n) sw[t] = expf(sw[t] - mx);
  __syncthreads();
  if (t < 64) {  // wave 0: sum reduce
    float s = 0.f;
    if (t < n) s = sw[t];
    if (t + 64 < n) s += sw[t + 64];
    for (int o = 32; o > 0; o >>= 1) s += __shfl_down(s, o);
    if (t == 0) sred[1] = s;
  }
  __syncthreads();
  float inv = (n > 0) ? 1.0f / sred[1] : 0.f;
  float acc = 0.f;
  for (int k = 0; k < n; ++k)
    acc = fmaf(sw[k], h[(size_t)sc[k] * D_OUT + t], acc);
  acc = leaky_f(acc * inv);
  // out tuple: mu = out[:, :64] flat first, then logvar = out[:, 64:]
  if (t < 64) out[(size_t)i * 64 + t] = acc;
  else        out[(size_t)NROW * 64 + (size_t)i * 64 + (t - 64)] = acc;
}

extern "C" void kernel_launch(void* const* d_in, const int* in_sizes, int n_in,
                              void* d_out, int out_size, void* d_ws, size_t ws_size,
                              hipStream_t stream) {
  const float* x   = (const float*)d_in[0];
  const float* adj = (const float*)d_in[1];
  const float* W1  = (const float*)d_in[2];
  const float* b1  = (const float*)d_in[3];
  const float* W2  = (const float*)d_in[4];
  const float* b2  = (const float*)d_in[5];
  const float* Wg  = (const float*)d_in[6];
  const float* a   = (const float*)d_in[7];
  float* out = (float*)d_out;

  char* ws = (char*)d_ws;
  int*   row_cnt  = (int*)  (ws + 0);          //   32 KB
  int*   row_cols = (int*)  (ws + 32768);      // 4 MB
  float* row_vals = (float*)(ws + 4227072);    // 4 MB
  u16*   B1t      = (u16*)  (ws + 8421376);    // 768 KB (256 x 1536)
  u16*   B2t      = (u16*)  (ws + 9207808);    // 384 KB (256 x 768)
  u16*   B3t      = (u16*)  (ws + 9601024);    // 192 KB (128 x 768)
  float* s1       = (float*)(ws + 9797632);    //  32 KB
  float* s2       = (float*)(ws + 9830400);    //  32 KB
  float* h        = (float*)(ws + 9863168);    // 4 MB (8192 x 128)
  float* H0T2     = (float*)(ws + 14057472);   // 8 MB (8192 x 256), reused for T2
  u16*   Apack    = (u16*)  (ws + 22446080);   // 25.2 MB (8192 x 1536), reused A1/A2/A3

  // 1. CSR build (reads adj once — the 268 MB structural floor)
  k_csr<<<NROW, 256, 0, stream>>>(adj, row_cnt, row_cols, row_vals);
  // 2. pack input + all weights to split-bf16 (one dispatch)
  k_pack_all<<<17280, 256, 0, stream>>>(x, Apack, W1, B1t, W2, B2t, Wg, B3t);
  // 3. H0 = x @ W1   (split-bf16, K'=1536)
  k_gemm<<<dim3(D_HID / 64, NROW / 128), 256, 0, stream>>>(Apack, B1t, H0T2, D_HID, 3 * D_IN);
  // 4. x1 = leaky(adj @ H0 + b1) -> packed A2
  k_spmm_pack<<<NROW, 256, 0, stream>>>(H0T2, b1, row_cnt, row_cols, row_vals, Apack);
  // 5. T2 = x1 @ W2  (K'=768)
  k_gemm<<<dim3(D_HID / 64, NROW / 128), 256, 0, stream>>>(Apack, B2t, H0T2, D_HID, 3 * D_HID);
  // 6. x2 = leaky(adj @ T2 + b2) -> packed A3
  k_spmm_pack<<<NROW, 256, 0, stream>>>(H0T2, b2, row_cnt, row_cols, row_vals, Apack);
  // 7. h = x2 @ Wg   (K'=768, N=128)
  k_gemm<<<dim3(D_OUT / 64, NROW / 128), 256, 0, stream>>>(Apack, B3t, h, D_OUT, 3 * D_HID);
  // 8. s1/s2 logit projections
  k_sdot<<<NROW, 64, 0, stream>>>(h, a, s1, s2);
  // 9. masked softmax attention + aggregate + output split
  k_attn<<<NROW, 128, 0, stream>>>(h, s1, s2, row_cnt, row_cols, out);
}

// Round 4
// 502.217 us; speedup vs baseline: 1.0504x; 1.0312x over previous
//
#include <hip/hip_runtime.h>

typedef unsigned short u16;
typedef u16 u16x4 __attribute__((ext_vector_type(4)));
typedef __bf16 bf16x8 __attribute__((ext_vector_type(8)));
typedef float f32x4 __attribute__((ext_vector_type(4)));

#define NROW 8192
#define CAP 128
#define D_IN 512
#define D_HID 256
#define D_OUT 128

__device__ __forceinline__ float leaky_f(float x) { return x > 0.f ? x : 0.25f * x; }

__device__ __forceinline__ u16 f2bf_rne(float f) {
  unsigned u = __float_as_uint(f);
  u += 0x7fffu + ((u >> 16) & 1u);
  return (u16)(u >> 16);
}
__device__ __forceinline__ void split_bf16(float f, u16& hi, u16& lo) {
  hi = f2bf_rne(f);
  float fh = __uint_as_float(((unsigned)hi) << 16);
  lo = f2bf_rne(f - fh);
}

// ---------------- CSR build: adj (8192x8192 fp32) -> per-row (cols, vals, cnt) ----------------
__global__ __launch_bounds__(256) void k_csr(const float* __restrict__ adj,
    int* __restrict__ cnt, int* __restrict__ cols, float* __restrict__ vals) {
  int i = blockIdx.x;
  __shared__ int c;
  if (threadIdx.x == 0) c = 0;
  __syncthreads();
  const float4* row = (const float4*)(adj + (size_t)i * NROW);
  for (int j4 = threadIdx.x; j4 < NROW / 4; j4 += 256) {
    float4 v = row[j4];
    int base = j4 * 4;
    if (v.x > 0.f) { int s = atomicAdd(&c, 1); if (s < CAP) { cols[i*CAP+s] = base;   vals[i*CAP+s] = v.x; } }
    if (v.y > 0.f) { int s = atomicAdd(&c, 1); if (s < CAP) { cols[i*CAP+s] = base+1; vals[i*CAP+s] = v.y; } }
    if (v.z > 0.f) { int s = atomicAdd(&c, 1); if (s < CAP) { cols[i*CAP+s] = base+2; vals[i*CAP+s] = v.z; } }
    if (v.w > 0.f) { int s = atomicAdd(&c, 1); if (s < CAP) { cols[i*CAP+s] = base+3; vals[i*CAP+s] = v.w; } }
  }
  __syncthreads();
  if (threadIdx.x == 0) cnt[i] = (c < CAP) ? c : CAP;
}

// ---------------- fused pack (2K split layout [hi|lo]) ----------------
// block regions: [0,16384) x | [16384,16896) W1 | [16896,17152) W2 | [17152,17280) Wg
__global__ __launch_bounds__(256) void k_pack_all(const float* __restrict__ X, u16* __restrict__ Ap,
    const float* __restrict__ W1, u16* __restrict__ B1,
    const float* __restrict__ W2, u16* __restrict__ B2,
    const float* __restrict__ Wg, u16* __restrict__ B3) {
  int b = blockIdx.x;
  if (b < 16384) {
    size_t id = (size_t)b * 256 + threadIdx.x;   // NROW*D_IN threads
    int k = (int)(id & 511);
    size_t i = id >> 9;
    float f = X[id];
    u16 hi, lo; split_bf16(f, hi, lo);
    size_t ro = i * 1024;                        // row = [hi(512) | lo(512)]
    Ap[ro + k] = hi; Ap[ro + 512 + k] = lo;
    return;
  }
  const float* W; u16* Bt; int K, Nc, id;
  if (b < 16896)      { W = W1; Bt = B1; K = D_IN;  Nc = D_HID; id = (b - 16384) * 256 + threadIdx.x; }
  else if (b < 17152) { W = W2; Bt = B2; K = D_HID; Nc = D_HID; id = (b - 16896) * 256 + threadIdx.x; }
  else                { W = Wg; Bt = B3; K = D_HID; Nc = D_OUT; id = (b - 17152) * 256 + threadIdx.x; }
  if (id >= K * Nc) return;
  int n = id % Nc, k = id / Nc;
  float f = W[id];
  u16 hi, lo; split_bf16(f, hi, lo);
  size_t ro = (size_t)n * 2 * K;                 // row = [hi(K) | lo(K)]
  Bt[ro + k] = hi; Bt[ro + K + k] = lo;
}

// ---------------- GEMM: C[M][N] = A @ Bt^T, emulated-fp32 via 3 bf16 products ----------------
// A rows: [hi(K)|lo(K)], Bt rows: [hi(K)|lo(K)]. acc += Ah*Bh + Ah*Bl + Al*Bh.
// tile BM=64 x BN=128, BK=32 true-K, 4 waves: wave w -> rows [16w,16w+16) x 128 cols.
// If aptr != nullptr: fused epilogue computes s1=h@a[0:128], s2=h@a[128:256] (requires BN==N==128).
__global__ __launch_bounds__(256) void k_gemm(const u16* __restrict__ A, const u16* __restrict__ Bt,
    float* __restrict__ C, int N, int K,
    const float* __restrict__ aptr, float* __restrict__ s1, float* __restrict__ s2) {
  __shared__ u16 Ah[64 * 40], Al[64 * 40];       // 5 KB each
  __shared__ u16 Bh[128 * 40], Bl[128 * 40];     // 10 KB each
  int tid = threadIdx.x;
  int bm = blockIdx.y * 64, bn = blockIdx.x * 128;
  int wave = tid >> 6, lane = tid & 63, l15 = lane & 15, quad = lane >> 4;
  f32x4 acc[8] = {};
  int ar = tid >> 2, aj = (tid & 3) << 3;        // A: 64 rows x 4 uint4 -> 1 per thread
  int br = tid >> 1, bj0 = (tid & 1) << 4;       // B: 128 rows x 4 uint4 -> 2 per thread
  const u16* Arow = A + (size_t)(bm + ar) * (2 * K);
  const u16* Brow = Bt + (size_t)(bn + br) * (2 * K);
  for (int k0 = 0; k0 < K; k0 += 32) {
    *(uint4*)(&Ah[ar * 40 + aj]) = *(const uint4*)(Arow + k0 + aj);
    *(uint4*)(&Al[ar * 40 + aj]) = *(const uint4*)(Arow + K + k0 + aj);
#pragma unroll
    for (int jj = 0; jj < 2; ++jj) {
      *(uint4*)(&Bh[br * 40 + bj0 + jj * 8]) = *(const uint4*)(Brow + k0 + bj0 + jj * 8);
      *(uint4*)(&Bl[br * 40 + bj0 + jj * 8]) = *(const uint4*)(Brow + K + k0 + bj0 + jj * 8);
    }
    __syncthreads();
    bf16x8 afh = *(const bf16x8*)(&Ah[(wave * 16 + l15) * 40 + quad * 8]);
    bf16x8 afl = *(const bf16x8*)(&Al[(wave * 16 + l15) * 40 + quad * 8]);
#pragma unroll
    for (int c = 0; c < 8; ++c) {
      bf16x8 bfh = *(const bf16x8*)(&Bh[(c * 16 + l15) * 40 + quad * 8]);
      bf16x8 bfl = *(const bf16x8*)(&Bl[(c * 16 + l15) * 40 + quad * 8]);
      acc[c] = __builtin_amdgcn_mfma_f32_16x16x32_bf16(afh, bfh, acc[c], 0, 0, 0);
      acc[c] = __builtin_amdgcn_mfma_f32_16x16x32_bf16(afh, bfl, acc[c], 0, 0, 0);
      acc[c] = __builtin_amdgcn_mfma_f32_16x16x32_bf16(afl, bfh, acc[c], 0, 0, 0);
    }
    __syncthreads();
  }
  // C/D layout: col = lane&15, row = quad*4 + reg
#pragma unroll
  for (int c = 0; c < 8; ++c)
#pragma unroll
    for (int rg = 0; rg < 4; ++rg) {
      int rowi = bm + wave * 16 + quad * 4 + rg;
      int coli = bn + c * 16 + l15;
      C[(size_t)rowi * N + coli] = acc[c][rg];
    }
  if (aptr) {  // fused h@a1 / h@a2 (BN==N==128): per-row dot + 16-lane shuffle reduce
    float a1v[8], a2v[8];
#pragma unroll
    for (int c = 0; c < 8; ++c) { a1v[c] = aptr[c * 16 + l15]; a2v[c] = aptr[128 + c * 16 + l15]; }
#pragma unroll
    for (int rg = 0; rg < 4; ++rg) {
      float p1 = 0.f, p2 = 0.f;
#pragma unroll
      for (int c = 0; c < 8; ++c) { p1 = fmaf(acc[c][rg], a1v[c], p1); p2 = fmaf(acc[c][rg], a2v[c], p2); }
#pragma unroll
      for (int m = 1; m < 16; m <<= 1) { p1 += __shfl_xor(p1, m); p2 += __shfl_xor(p2, m); }
      if (l15 == 0) {
        int rowi = bm + wave * 16 + quad * 4 + rg;
        s1[rowi] = p1; s2[rowi] = p2;
      }
    }
  }
}

// ---------------- SpMM + bias + leaky + 2K-split-pack (float4 gather, 4-way n-split) ----------------
__global__ __launch_bounds__(256) void k_spmm_pack(const float* __restrict__ Hin,
    const float* __restrict__ bias, const int* __restrict__ cnt,
    const int* __restrict__ cols, const float* __restrict__ vals, u16* __restrict__ Ap) {
  int i = blockIdx.x, t = threadIdx.x;
  int t64 = t & 63, g = t >> 6;
  __shared__ int sc[CAP];
  __shared__ float sv[CAP];
  __shared__ float4 sacc[4][64];
  int n = cnt[i];
  if (t < n) { sc[t] = cols[i * CAP + t]; sv[t] = vals[i * CAP + t]; }
  __syncthreads();
  float4 acc = {0.f, 0.f, 0.f, 0.f};
  const float4* H4 = (const float4*)Hin;
  for (int k = g; k < n; k += 4) {
    float w = sv[k];
    float4 v = H4[(size_t)sc[k] * 64 + t64];
    acc.x = fmaf(w, v.x, acc.x); acc.y = fmaf(w, v.y, acc.y);
    acc.z = fmaf(w, v.z, acc.z); acc.w = fmaf(w, v.w, acc.w);
  }
  sacc[g][t64] = acc;
  __syncthreads();
  if (t < 64) {
    float4 a0 = sacc[0][t], a1 = sacc[1][t], a2 = sacc[2][t], a3 = sacc[3][t];
    float4 bv = ((const float4*)bias)[t];
    float r[4] = { leaky_f(a0.x + a1.x + a2.x + a3.x + bv.x),
                   leaky_f(a0.y + a1.y + a2.y + a3.y + bv.y),
                   leaky_f(a0.z + a1.z + a2.z + a3.z + bv.z),
                   leaky_f(a0.w + a1.w + a2.w + a3.w + bv.w) };
    u16x4 hi4, lo4;
#pragma unroll
    for (int e = 0; e < 4; ++e) { u16 hh, ll; split_bf16(r[e], hh, ll); hi4[e] = hh; lo4[e] = ll; }
    size_t ro = (size_t)i * 512;                 // row = [hi(256) | lo(256)]
    *(u16x4*)(Ap + ro + 4 * t) = hi4;
    *(u16x4*)(Ap + ro + 256 + 4 * t) = lo4;
  }
}

// ---------------- attention: neighbor softmax + float4 aggregate + leaky + mu/logvar split ----------------
__global__ __launch_bounds__(128) void k_attn(const float* __restrict__ h,
    const float* __restrict__ s1, const float* __restrict__ s2,
    const int* __restrict__ cnt, const int* __restrict__ cols, float* __restrict__ out) {
  int i = blockIdx.x, t = threadIdx.x;
  int t32 = t & 31, g = t >> 5;
  __shared__ int sc[CAP];
  __shared__ float sw[CAP];
  __shared__ float sred[2];
  __shared__ float4 sacc[4][32];
  int n = cnt[i];
  float s1i = s1[i];
  if (t < n) { int c = cols[i * CAP + t]; sc[t] = c; sw[t] = leaky_f(s1i + s2[c]); }
  __syncthreads();
  if (t < 64) {
    float m = -1e30f;
    if (t < n) m = sw[t];
    if (t + 64 < n) m = fmaxf(m, sw[t + 64]);
    for (int o = 32; o > 0; o >>= 1) m = fmaxf(m, __shfl_down(m, o));
    if (t == 0) sred[0] = m;
  }
  __syncthreads();
  float mx = sred[0];
  if (t < n) sw[t] = expf(sw[t] - mx);
  __syncthreads();
  if (t < 64) {
    float s = 0.f;
    if (t < n) s = sw[t];
    if (t + 64 < n) s += sw[t + 64];
    for (int o = 32; o > 0; o >>= 1) s += __shfl_down(s, o);
    if (t == 0) sred[1] = s;
  }
  __syncthreads();
  float inv = (n > 0) ? 1.0f / sred[1] : 0.f;
  float4 acc = {0.f, 0.f, 0.f, 0.f};
  const float4* h4 = (const float4*)h;
  for (int k = g; k < n; k += 4) {
    float w = sw[k];
    float4 v = h4[(size_t)sc[k] * 32 + t32];
    acc.x = fmaf(w, v.x, acc.x); acc.y = fmaf(w, v.y, acc.y);
    acc.z = fmaf(w, v.z, acc.z); acc.w = fmaf(w, v.w, acc.w);
  }
  sacc[g][t32] = acc;
  __syncthreads();
  if (t < 32) {
    float4 a0 = sacc[0][t], a1 = sacc[1][t], a2 = sacc[2][t], a3 = sacc[3][t];
    float4 r;
    r.x = leaky_f((a0.x + a1.x + a2.x + a3.x) * inv);
    r.y = leaky_f((a0.y + a1.y + a2.y + a3.y) * inv);
    r.z = leaky_f((a0.z + a1.z + a2.z + a3.z) * inv);
    r.w = leaky_f((a0.w + a1.w + a2.w + a3.w) * inv);
    float4* o4 = (float4*)out;
    // cols [4t,4t+4): t<16 -> mu (out[:, :64]), else logvar (out[:, 64:])
    if (t < 16) o4[(size_t)i * 16 + t] = r;
    else        o4[(size_t)NROW * 16 + (size_t)i * 16 + (t - 16)] = r;
  }
}

extern "C" void kernel_launch(void* const* d_in, const int* in_sizes, int n_in,
                              void* d_out, int out_size, void* d_ws, size_t ws_size,
                              hipStream_t stream) {
  const float* x   = (const float*)d_in[0];
  const float* adj = (const float*)d_in[1];
  const float* W1  = (const float*)d_in[2];
  const float* b1  = (const float*)d_in[3];
  const float* W2  = (const float*)d_in[4];
  const float* b2  = (const float*)d_in[5];
  const float* Wg  = (const float*)d_in[6];
  const float* a   = (const float*)d_in[7];
  float* out = (float*)d_out;

  char* ws = (char*)d_ws;
  int*   row_cnt  = (int*)  (ws + 0);          //  32 KB
  int*   row_cols = (int*)  (ws + 32768);      //   4 MB
  float* row_vals = (float*)(ws + 4227072);    //   4 MB
  u16*   B1t      = (u16*)  (ws + 8421376);    // 512 KB (256 x 1024)
  u16*   B2t      = (u16*)  (ws + 8945664);    // 256 KB (256 x 512)
  u16*   B3t      = (u16*)  (ws + 9207808);    // 128 KB (128 x 512)
  float* s1       = (float*)(ws + 9338880);    //  32 KB
  float* s2       = (float*)(ws + 9371648);    //  32 KB
  float* h        = (float*)(ws + 9404416);    //   4 MB (8192 x 128)
  float* H0T2     = (float*)(ws + 13598720);   //   8 MB (8192 x 256)
  u16*   Apack    = (u16*)  (ws + 21987328);   //  16 MB (8192 x 1024), reused A1/A2/A3

  // 1. CSR build (268 MB adj read — the structural floor)
  k_csr<<<NROW, 256, 0, stream>>>(adj, row_cnt, row_cols, row_vals);
  // 2. pack input + weights to [hi|lo] split-bf16
  k_pack_all<<<17280, 256, 0, stream>>>(x, Apack, W1, B1t, W2, B2t, Wg, B3t);
  // 3. H0 = x @ W1  (K=512)  — BM=64 => grid.y must be NROW/64 = 128 (R3 bug: was 64)
  k_gemm<<<dim3(2, 128), 256, 0, stream>>>(Apack, B1t, H0T2, D_HID, D_IN, nullptr, nullptr, nullptr);
  // 4. x1 = leaky(adj @ H0 + b1) -> packed A2
  k_spmm_pack<<<NROW, 256, 0, stream>>>(H0T2, b1, row_cnt, row_cols, row_vals, Apack);
  // 5. T2 = x1 @ W2  (K=256)
  k_gemm<<<dim3(2, 128), 256, 0, stream>>>(Apack, B2t, H0T2, D_HID, D_HID, nullptr, nullptr, nullptr);
  // 6. x2 = leaky(adj @ T2 + b2) -> packed A3
  k_spmm_pack<<<NROW, 256, 0, stream>>>(H0T2, b2, row_cnt, row_cols, row_vals, Apack);
  // 7. h = x2 @ Wg (K=256, N=128) + fused s1/s2 epilogue
  k_gemm<<<dim3(1, 128), 256, 0, stream>>>(Apack, B3t, h, D_OUT, D_HID, a, s1, s2);
  // 8. masked softmax attention + aggregate + output split
  k_attn<<<NROW, 128, 0, stream>>>(h, s1, s2, row_cnt, row_cols, out);
}

// Round 5
// 494.834 us; speedup vs baseline: 1.0660x; 1.0149x over previous
//
#include <hip/hip_runtime.h>

typedef unsigned short u16;
typedef u16 u16x4 __attribute__((ext_vector_type(4)));
typedef __bf16 bf16x8 __attribute__((ext_vector_type(8)));
typedef float f32x4 __attribute__((ext_vector_type(4)));

#define NROW 8192
#define CAP 128
#define D_IN 512
#define D_HID 256
#define D_OUT 128

__device__ __forceinline__ float leaky_f(float x) { return x > 0.f ? x : 0.25f * x; }

__device__ __forceinline__ u16 f2bf_rne(float f) {
  unsigned u = __float_as_uint(f);
  u += 0x7fffu + ((u >> 16) & 1u);
  return (u16)(u >> 16);
}
__device__ __forceinline__ void split_bf16(float f, u16& hi, u16& lo) {
  hi = f2bf_rne(f);
  float fh = __uint_as_float(((unsigned)hi) << 16);
  lo = f2bf_rne(f - fh);
}

// ---------------- CSR build + weight pack (merged dispatch) ----------------
// blocks [0,8192): CSR row build from adj. blocks [8192,9088): pack W1/W2/Wg -> [hi|lo] Bt.
__global__ __launch_bounds__(256) void k_csr_packw(const float* __restrict__ adj,
    int* __restrict__ cnt, int* __restrict__ cols, float* __restrict__ vals,
    const float* __restrict__ W1, u16* __restrict__ B1,
    const float* __restrict__ W2, u16* __restrict__ B2,
    const float* __restrict__ Wg, u16* __restrict__ B3) {
  int b = blockIdx.x;
  if (b < NROW) {
    int i = b;
    __shared__ int c;
    if (threadIdx.x == 0) c = 0;
    __syncthreads();
    const float4* row = (const float4*)(adj + (size_t)i * NROW);
    for (int j4 = threadIdx.x; j4 < NROW / 4; j4 += 256) {
      float4 v = row[j4];
      int base = j4 * 4;
      if (v.x > 0.f) { int s = atomicAdd(&c, 1); if (s < CAP) { cols[i*CAP+s] = base;   vals[i*CAP+s] = v.x; } }
      if (v.y > 0.f) { int s = atomicAdd(&c, 1); if (s < CAP) { cols[i*CAP+s] = base+1; vals[i*CAP+s] = v.y; } }
      if (v.z > 0.f) { int s = atomicAdd(&c, 1); if (s < CAP) { cols[i*CAP+s] = base+2; vals[i*CAP+s] = v.z; } }
      if (v.w > 0.f) { int s = atomicAdd(&c, 1); if (s < CAP) { cols[i*CAP+s] = base+3; vals[i*CAP+s] = v.w; } }
    }
    __syncthreads();
    if (threadIdx.x == 0) cnt[i] = (c < CAP) ? c : CAP;
    return;
  }
  const float* W; u16* Bt; int K, Nc, id;
  int pb = b - NROW;                       // 896 pack blocks: 512 | 256 | 128
  if (pb < 512)      { W = W1; Bt = B1; K = D_IN;  Nc = D_HID; id = pb * 256 + threadIdx.x; }
  else if (pb < 768) { W = W2; Bt = B2; K = D_HID; Nc = D_HID; id = (pb - 512) * 256 + threadIdx.x; }
  else               { W = Wg; Bt = B3; K = D_HID; Nc = D_OUT; id = (pb - 768) * 256 + threadIdx.x; }
  int n = id % Nc, k = id / Nc;
  float f = W[id];
  u16 hi, lo; split_bf16(f, hi, lo);
  size_t ro = (size_t)n * 2 * K;           // row = [hi(K) | lo(K)]
  Bt[ro + k] = hi; Bt[ro + K + k] = lo;
}

// ---------------- GEMM1: C = x @ Bt^T with in-register fp32->split-bf16 of x ----------------
// x fp32 [M][K]; Bt rows [hi(K)|lo(K)]. Same math as packed path (identical split_bf16).
__global__ __launch_bounds__(256) void k_gemm_x(const float* __restrict__ X, const u16* __restrict__ Bt,
    float* __restrict__ C, int N, int K) {
  __shared__ u16 Ah[64 * 40], Al[64 * 40];
  __shared__ u16 Bh[128 * 40], Bl[128 * 40];
  int tid = threadIdx.x;
  int bm = blockIdx.y * 64, bn = blockIdx.x * 128;
  int wave = tid >> 6, lane = tid & 63, l15 = lane & 15, quad = lane >> 4;
  f32x4 acc[8] = {};
  int ar = tid >> 2, aj = (tid & 3) << 3;        // A: 64 rows, 8 K-slots per thread
  int br = tid >> 1, bj0 = (tid & 1) << 4;       // B: 128 rows, 2 uint4 per thread
  const float* Xrow = X + (size_t)(bm + ar) * K + aj;
  const u16* Brow = Bt + (size_t)(bn + br) * (2 * K);
  for (int k0 = 0; k0 < K; k0 += 32) {
    alignas(16) u16 hh[8], ll[8];
    float xv[8];
    *(float4*)(xv)     = *(const float4*)(Xrow + k0);
    *(float4*)(xv + 4) = *(const float4*)(Xrow + k0 + 4);
#pragma unroll
    for (int e = 0; e < 8; ++e) split_bf16(xv[e], hh[e], ll[e]);
    *(uint4*)(&Ah[ar * 40 + aj]) = *(const uint4*)hh;
    *(uint4*)(&Al[ar * 40 + aj]) = *(const uint4*)ll;
#pragma unroll
    for (int jj = 0; jj < 2; ++jj) {
      *(uint4*)(&Bh[br * 40 + bj0 + jj * 8]) = *(const uint4*)(Brow + k0 + bj0 + jj * 8);
      *(uint4*)(&Bl[br * 40 + bj0 + jj * 8]) = *(const uint4*)(Brow + K + k0 + bj0 + jj * 8);
    }
    __syncthreads();
    bf16x8 afh = *(const bf16x8*)(&Ah[(wave * 16 + l15) * 40 + quad * 8]);
    bf16x8 afl = *(const bf16x8*)(&Al[(wave * 16 + l15) * 40 + quad * 8]);
#pragma unroll
    for (int c = 0; c < 8; ++c) {
      bf16x8 bfh = *(const bf16x8*)(&Bh[(c * 16 + l15) * 40 + quad * 8]);
      bf16x8 bfl = *(const bf16x8*)(&Bl[(c * 16 + l15) * 40 + quad * 8]);
      acc[c] = __builtin_amdgcn_mfma_f32_16x16x32_bf16(afh, bfh, acc[c], 0, 0, 0);
      acc[c] = __builtin_amdgcn_mfma_f32_16x16x32_bf16(afh, bfl, acc[c], 0, 0, 0);
      acc[c] = __builtin_amdgcn_mfma_f32_16x16x32_bf16(afl, bfh, acc[c], 0, 0, 0);
    }
    __syncthreads();
  }
#pragma unroll
  for (int c = 0; c < 8; ++c)
#pragma unroll
    for (int rg = 0; rg < 4; ++rg) {
      int rowi = bm + wave * 16 + quad * 4 + rg;   // C/D: col=lane&15, row=quad*4+reg
      int coli = bn + c * 16 + l15;
      C[(size_t)rowi * N + coli] = acc[c][rg];
    }
}

// ---------------- GEMM (packed A): C = A @ Bt^T; optional fused s1/s2 epilogue ----------------
__global__ __launch_bounds__(256) void k_gemm(const u16* __restrict__ A, const u16* __restrict__ Bt,
    float* __restrict__ C, int N, int K,
    const float* __restrict__ aptr, float* __restrict__ s1, float* __restrict__ s2) {
  __shared__ u16 Ah[64 * 40], Al[64 * 40];
  __shared__ u16 Bh[128 * 40], Bl[128 * 40];
  int tid = threadIdx.x;
  int bm = blockIdx.y * 64, bn = blockIdx.x * 128;
  int wave = tid >> 6, lane = tid & 63, l15 = lane & 15, quad = lane >> 4;
  f32x4 acc[8] = {};
  int ar = tid >> 2, aj = (tid & 3) << 3;
  int br = tid >> 1, bj0 = (tid & 1) << 4;
  const u16* Arow = A + (size_t)(bm + ar) * (2 * K);
  const u16* Brow = Bt + (size_t)(bn + br) * (2 * K);
  for (int k0 = 0; k0 < K; k0 += 32) {
    *(uint4*)(&Ah[ar * 40 + aj]) = *(const uint4*)(Arow + k0 + aj);
    *(uint4*)(&Al[ar * 40 + aj]) = *(const uint4*)(Arow + K + k0 + aj);
#pragma unroll
    for (int jj = 0; jj < 2; ++jj) {
      *(uint4*)(&Bh[br * 40 + bj0 + jj * 8]) = *(const uint4*)(Brow + k0 + bj0 + jj * 8);
      *(uint4*)(&Bl[br * 40 + bj0 + jj * 8]) = *(const uint4*)(Brow + K + k0 + bj0 + jj * 8);
    }
    __syncthreads();
    bf16x8 afh = *(const bf16x8*)(&Ah[(wave * 16 + l15) * 40 + quad * 8]);
    bf16x8 afl = *(const bf16x8*)(&Al[(wave * 16 + l15) * 40 + quad * 8]);
#pragma unroll
    for (int c = 0; c < 8; ++c) {
      bf16x8 bfh = *(const bf16x8*)(&Bh[(c * 16 + l15) * 40 + quad * 8]);
      bf16x8 bfl = *(const bf16x8*)(&Bl[(c * 16 + l15) * 40 + quad * 8]);
      acc[c] = __builtin_amdgcn_mfma_f32_16x16x32_bf16(afh, bfh, acc[c], 0, 0, 0);
      acc[c] = __builtin_amdgcn_mfma_f32_16x16x32_bf16(afh, bfl, acc[c], 0, 0, 0);
      acc[c] = __builtin_amdgcn_mfma_f32_16x16x32_bf16(afl, bfh, acc[c], 0, 0, 0);
    }
    __syncthreads();
  }
#pragma unroll
  for (int c = 0; c < 8; ++c)
#pragma unroll
    for (int rg = 0; rg < 4; ++rg) {
      int rowi = bm + wave * 16 + quad * 4 + rg;
      int coli = bn + c * 16 + l15;
      C[(size_t)rowi * N + coli] = acc[c][rg];
    }
  if (aptr) {  // fused h@a1 / h@a2 (BN==N==128)
    float a1v[8], a2v[8];
#pragma unroll
    for (int c = 0; c < 8; ++c) { a1v[c] = aptr[c * 16 + l15]; a2v[c] = aptr[128 + c * 16 + l15]; }
#pragma unroll
    for (int rg = 0; rg < 4; ++rg) {
      float p1 = 0.f, p2 = 0.f;
#pragma unroll
      for (int c = 0; c < 8; ++c) { p1 = fmaf(acc[c][rg], a1v[c], p1); p2 = fmaf(acc[c][rg], a2v[c], p2); }
#pragma unroll
      for (int m = 1; m < 16; m <<= 1) { p1 += __shfl_xor(p1, m); p2 += __shfl_xor(p2, m); }
      if (l15 == 0) {
        int rowi = bm + wave * 16 + quad * 4 + rg;
        s1[rowi] = p1; s2[rowi] = p2;
      }
    }
  }
}

// ---------------- SpMM + bias + leaky + 2K-split-pack ----------------
__global__ __launch_bounds__(256) void k_spmm_pack(const float* __restrict__ Hin,
    const float* __restrict__ bias, const int* __restrict__ cnt,
    const int* __restrict__ cols, const float* __restrict__ vals, u16* __restrict__ Ap) {
  int i = blockIdx.x, t = threadIdx.x;
  int t64 = t & 63, g = t >> 6;
  __shared__ int sc[CAP];
  __shared__ float sv[CAP];
  __shared__ float4 sacc[4][64];
  int n = cnt[i];
  if (t < n) { sc[t] = cols[i * CAP + t]; sv[t] = vals[i * CAP + t]; }
  __syncthreads();
  float4 acc = {0.f, 0.f, 0.f, 0.f};
  const float4* H4 = (const float4*)Hin;
  for (int k = g; k < n; k += 4) {
    float w = sv[k];
    float4 v = H4[(size_t)sc[k] * 64 + t64];
    acc.x = fmaf(w, v.x, acc.x); acc.y = fmaf(w, v.y, acc.y);
    acc.z = fmaf(w, v.z, acc.z); acc.w = fmaf(w, v.w, acc.w);
  }
  sacc[g][t64] = acc;
  __syncthreads();
  if (t < 64) {
    float4 a0 = sacc[0][t], a1 = sacc[1][t], a2 = sacc[2][t], a3 = sacc[3][t];
    float4 bv = ((const float4*)bias)[t];
    float r[4] = { leaky_f(a0.x + a1.x + a2.x + a3.x + bv.x),
                   leaky_f(a0.y + a1.y + a2.y + a3.y + bv.y),
                   leaky_f(a0.z + a1.z + a2.z + a3.z + bv.z),
                   leaky_f(a0.w + a1.w + a2.w + a3.w + bv.w) };
    u16x4 hi4, lo4;
#pragma unroll
    for (int e = 0; e < 4; ++e) { u16 hh, ll; split_bf16(r[e], hh, ll); hi4[e] = hh; lo4[e] = ll; }
    size_t ro = (size_t)i * 512;                 // row = [hi(256) | lo(256)]
    *(u16x4*)(Ap + ro + 4 * t) = hi4;
    *(u16x4*)(Ap + ro + 256 + 4 * t) = lo4;
  }
}

// ---------------- attention: neighbor softmax + aggregate + leaky + mu/logvar split ----------------
__global__ __launch_bounds__(128) void k_attn(const float* __restrict__ h,
    const float* __restrict__ s1, const float* __restrict__ s2,
    const int* __restrict__ cnt, const int* __restrict__ cols, float* __restrict__ out) {
  int i = blockIdx.x, t = threadIdx.x;
  int t32 = t & 31, g = t >> 5;
  __shared__ int sc[CAP];
  __shared__ float sw[CAP];
  __shared__ float sred[2];
  __shared__ float4 sacc[4][32];
  int n = cnt[i];
  float s1i = s1[i];
  if (t < n) { int c = cols[i * CAP + t]; sc[t] = c; sw[t] = leaky_f(s1i + s2[c]); }
  __syncthreads();
  if (t < 64) {
    float m = -1e30f;
    if (t < n) m = sw[t];
    if (t + 64 < n) m = fmaxf(m, sw[t + 64]);
    for (int o = 32; o > 0; o >>= 1) m = fmaxf(m, __shfl_down(m, o));
    if (t == 0) sred[0] = m;
  }
  __syncthreads();
  float mx = sred[0];
  if (t < n) sw[t] = expf(sw[t] - mx);
  __syncthreads();
  if (t < 64) {
    float s = 0.f;
    if (t < n) s = sw[t];
    if (t + 64 < n) s += sw[t + 64];
    for (int o = 32; o > 0; o >>= 1) s += __shfl_down(s, o);
    if (t == 0) sred[1] = s;
  }
  __syncthreads();
  float inv = (n > 0) ? 1.0f / sred[1] : 0.f;
  float4 acc = {0.f, 0.f, 0.f, 0.f};
  const float4* h4 = (const float4*)h;
  for (int k = g; k < n; k += 4) {
    float w = sw[k];
    float4 v = h4[(size_t)sc[k] * 32 + t32];
    acc.x = fmaf(w, v.x, acc.x); acc.y = fmaf(w, v.y, acc.y);
    acc.z = fmaf(w, v.z, acc.z); acc.w = fmaf(w, v.w, acc.w);
  }
  sacc[g][t32] = acc;
  __syncthreads();
  if (t < 32) {
    float4 a0 = sacc[0][t], a1 = sacc[1][t], a2 = sacc[2][t], a3 = sacc[3][t];
    float4 r;
    r.x = leaky_f((a0.x + a1.x + a2.x + a3.x) * inv);
    r.y = leaky_f((a0.y + a1.y + a2.y + a3.y) * inv);
    r.z = leaky_f((a0.z + a1.z + a2.z + a3.z) * inv);
    r.w = leaky_f((a0.w + a1.w + a2.w + a3.w) * inv);
    float4* o4 = (float4*)out;
    if (t < 16) o4[(size_t)i * 16 + t] = r;                               // mu
    else        o4[(size_t)NROW * 16 + (size_t)i * 16 + (t - 16)] = r;    // logvar
  }
}

extern "C" void kernel_launch(void* const* d_in, const int* in_sizes, int n_in,
                              void* d_out, int out_size, void* d_ws, size_t ws_size,
                              hipStream_t stream) {
  const float* x   = (const float*)d_in[0];
  const float* adj = (const float*)d_in[1];
  const float* W1  = (const float*)d_in[2];
  const float* b1  = (const float*)d_in[3];
  const float* W2  = (const float*)d_in[4];
  const float* b2  = (const float*)d_in[5];
  const float* Wg  = (const float*)d_in[6];
  const float* a   = (const float*)d_in[7];
  float* out = (float*)d_out;

  char* ws = (char*)d_ws;
  int*   row_cnt  = (int*)  (ws + 0);          //  32 KB
  int*   row_cols = (int*)  (ws + 32768);      //   4 MB
  float* row_vals = (float*)(ws + 4227072);    //   4 MB
  u16*   B1t      = (u16*)  (ws + 8421376);    // 512 KB (256 x 1024)
  u16*   B2t      = (u16*)  (ws + 8945664);    // 256 KB (256 x 512)
  u16*   B3t      = (u16*)  (ws + 9207808);    // 128 KB (128 x 512)
  float* s1       = (float*)(ws + 9338880);    //  32 KB
  float* s2       = (float*)(ws + 9371648);    //  32 KB
  float* h        = (float*)(ws + 9404416);    //   4 MB (8192 x 128)
  float* H0T2     = (float*)(ws + 13598720);   //   8 MB (8192 x 256)
  u16*   Apack    = (u16*)  (ws + 21987328);   //   8 MB (8192 x 512), x1/x2 packed

  // 1. CSR build (268 MB adj read — structural floor) + weight pack, one dispatch
  k_csr_packw<<<NROW + 896, 256, 0, stream>>>(adj, row_cnt, row_cols, row_vals,
                                              W1, B1t, W2, B2t, Wg, B3t);
  // 2. H0 = x @ W1  (x split to bf16 hi/lo in-register; K=512)
  k_gemm_x<<<dim3(2, 128), 256, 0, stream>>>(x, B1t, H0T2, D_HID, D_IN);
  // 3. x1 = leaky(adj @ H0 + b1) -> packed
  k_spmm_pack<<<NROW, 256, 0, stream>>>(H0T2, b1, row_cnt, row_cols, row_vals, Apack);
  // 4. T2 = x1 @ W2  (K=256)
  k_gemm<<<dim3(2, 128), 256, 0, stream>>>(Apack, B2t, H0T2, D_HID, D_HID, nullptr, nullptr, nullptr);
  // 5. x2 = leaky(adj @ T2 + b2) -> packed
  k_spmm_pack<<<NROW, 256, 0, stream>>>(H0T2, b2, row_cnt, row_cols, row_vals, Apack);
  // 6. h = x2 @ Wg (K=256, N=128) + fused s1/s2 epilogue
  k_gemm<<<dim3(1, 128), 256, 0, stream>>>(Apack, B3t, h, D_OUT, D_HID, a, s1, s2);
  // 7. masked softmax attention + aggregate + output split
  k_attn<<<NROW, 128, 0, stream>>>(h, s1, s2, row_cnt, row_cols, out);
}

// Round 6
// 494.405 us; speedup vs baseline: 1.0669x; 1.0009x over previous
//
#include <hip/hip_runtime.h>

typedef unsigned short u16;
typedef u16 u16x4 __attribute__((ext_vector_type(4)));
typedef __bf16 bf16x8 __attribute__((ext_vector_type(8)));
typedef float f32x4 __attribute__((ext_vector_type(4)));

#define NROW 8192
#define CAP 128
#define D_IN 512
#define D_HID 256
#define D_OUT 128

__device__ __forceinline__ float leaky_f(float x) { return x > 0.f ? x : 0.25f * x; }

__device__ __forceinline__ u16 f2bf_rne(float f) {
  unsigned u = __float_as_uint(f);
  u += 0x7fffu + ((u >> 16) & 1u);
  return (u16)(u >> 16);
}
__device__ __forceinline__ void split_bf16(float f, u16& hi, u16& lo) {
  hi = f2bf_rne(f);
  float fh = __uint_as_float(((unsigned)hi) << 16);
  lo = f2bf_rne(f - fh);
}

// ---------------- CSR build + weight pack (merged dispatch) ----------------
__global__ __launch_bounds__(256) void k_csr_packw(const float* __restrict__ adj,
    int* __restrict__ cnt, int* __restrict__ cols, float* __restrict__ vals,
    const float* __restrict__ W1, u16* __restrict__ B1,
    const float* __restrict__ W2, u16* __restrict__ B2,
    const float* __restrict__ Wg, u16* __restrict__ B3) {
  int b = blockIdx.x;
  if (b < NROW) {
    int i = b;
    __shared__ int c;
    if (threadIdx.x == 0) c = 0;
    __syncthreads();
    const float4* row = (const float4*)(adj + (size_t)i * NROW);
    for (int j4 = threadIdx.x; j4 < NROW / 4; j4 += 256) {
      float4 v = row[j4];
      int base = j4 * 4;
      if (v.x > 0.f) { int s = atomicAdd(&c, 1); if (s < CAP) { cols[i*CAP+s] = base;   vals[i*CAP+s] = v.x; } }
      if (v.y > 0.f) { int s = atomicAdd(&c, 1); if (s < CAP) { cols[i*CAP+s] = base+1; vals[i*CAP+s] = v.y; } }
      if (v.z > 0.f) { int s = atomicAdd(&c, 1); if (s < CAP) { cols[i*CAP+s] = base+2; vals[i*CAP+s] = v.z; } }
      if (v.w > 0.f) { int s = atomicAdd(&c, 1); if (s < CAP) { cols[i*CAP+s] = base+3; vals[i*CAP+s] = v.w; } }
    }
    __syncthreads();
    if (threadIdx.x == 0) cnt[i] = (c < CAP) ? c : CAP;
    return;
  }
  const float* W; u16* Bt; int K, Nc, id;
  int pb = b - NROW;                       // 896 pack blocks: 512 | 256 | 128
  if (pb < 512)      { W = W1; Bt = B1; K = D_IN;  Nc = D_HID; id = pb * 256 + threadIdx.x; }
  else if (pb < 768) { W = W2; Bt = B2; K = D_HID; Nc = D_HID; id = (pb - 512) * 256 + threadIdx.x; }
  else               { W = Wg; Bt = B3; K = D_HID; Nc = D_OUT; id = (pb - 768) * 256 + threadIdx.x; }
  int n = id % Nc, k = id / Nc;
  float f = W[id];
  u16 hi, lo; split_bf16(f, hi, lo);
  size_t ro = (size_t)n * 2 * K;           // row = [hi(K) | lo(K)]
  Bt[ro + k] = hi; Bt[ro + K + k] = lo;
}

// ---------------- GEMM1: 64x64 tile, x fp32 split in-register; grid (N/64, M/64) ----------------
__global__ __launch_bounds__(256) void k_gemm_x(const float* __restrict__ X, const u16* __restrict__ Bt,
    float* __restrict__ C, int N, int K) {
  __shared__ u16 Ah[64 * 40], Al[64 * 40];   // 5.1 KB each
  __shared__ u16 Bh[64 * 40], Bl[64 * 40];   // 20.5 KB total -> 2 blocks/CU at grid 512
  int tid = threadIdx.x;
  int bm = blockIdx.y * 64, bn = blockIdx.x * 64;
  int wave = tid >> 6, lane = tid & 63, l15 = lane & 15, quad = lane >> 4;
  f32x4 acc[4] = {};
  int ar = tid >> 2, aj = (tid & 3) << 3;      // 64 rows x 32 u16: 1 uint4-slot per thread
  const float* Xrow = X + (size_t)(bm + ar) * K + aj;
  const u16* Brow = Bt + (size_t)(bn + ar) * (2 * K) + aj;
  for (int k0 = 0; k0 < K; k0 += 32) {
    alignas(16) u16 hh[8], ll[8];
    float xv[8];
    *(float4*)(xv)     = *(const float4*)(Xrow + k0);
    *(float4*)(xv + 4) = *(const float4*)(Xrow + k0 + 4);
#pragma unroll
    for (int e = 0; e < 8; ++e) split_bf16(xv[e], hh[e], ll[e]);
    *(uint4*)(&Ah[ar * 40 + aj]) = *(const uint4*)hh;
    *(uint4*)(&Al[ar * 40 + aj]) = *(const uint4*)ll;
    *(uint4*)(&Bh[ar * 40 + aj]) = *(const uint4*)(Brow + k0);
    *(uint4*)(&Bl[ar * 40 + aj]) = *(const uint4*)(Brow + K + k0);
    __syncthreads();
    bf16x8 afh = *(const bf16x8*)(&Ah[(wave * 16 + l15) * 40 + quad * 8]);
    bf16x8 afl = *(const bf16x8*)(&Al[(wave * 16 + l15) * 40 + quad * 8]);
#pragma unroll
    for (int c = 0; c < 4; ++c) {
      bf16x8 bfh = *(const bf16x8*)(&Bh[(c * 16 + l15) * 40 + quad * 8]);
      bf16x8 bfl = *(const bf16x8*)(&Bl[(c * 16 + l15) * 40 + quad * 8]);
      acc[c] = __builtin_amdgcn_mfma_f32_16x16x32_bf16(afh, bfh, acc[c], 0, 0, 0);
      acc[c] = __builtin_amdgcn_mfma_f32_16x16x32_bf16(afh, bfl, acc[c], 0, 0, 0);
      acc[c] = __builtin_amdgcn_mfma_f32_16x16x32_bf16(afl, bfh, acc[c], 0, 0, 0);
    }
    __syncthreads();
  }
#pragma unroll
  for (int c = 0; c < 4; ++c)
#pragma unroll
    for (int rg = 0; rg < 4; ++rg) {
      int rowi = bm + wave * 16 + quad * 4 + rg;   // C/D: col=lane&15, row=quad*4+reg
      int coli = bn + c * 16 + l15;
      C[(size_t)rowi * N + coli] = acc[c][rg];
    }
}

// ---------------- GEMM2: 64x64 tile, packed A; grid (N/64, M/64) ----------------
__global__ __launch_bounds__(256) void k_gemm(const u16* __restrict__ A, const u16* __restrict__ Bt,
    float* __restrict__ C, int N, int K) {
  __shared__ u16 Ah[64 * 40], Al[64 * 40];
  __shared__ u16 Bh[64 * 40], Bl[64 * 40];
  int tid = threadIdx.x;
  int bm = blockIdx.y * 64, bn = blockIdx.x * 64;
  int wave = tid >> 6, lane = tid & 63, l15 = lane & 15, quad = lane >> 4;
  f32x4 acc[4] = {};
  int ar = tid >> 2, aj = (tid & 3) << 3;
  const u16* Arow = A + (size_t)(bm + ar) * (2 * K) + aj;
  const u16* Brow = Bt + (size_t)(bn + ar) * (2 * K) + aj;
  for (int k0 = 0; k0 < K; k0 += 32) {
    *(uint4*)(&Ah[ar * 40 + aj]) = *(const uint4*)(Arow + k0);
    *(uint4*)(&Al[ar * 40 + aj]) = *(const uint4*)(Arow + K + k0);
    *(uint4*)(&Bh[ar * 40 + aj]) = *(const uint4*)(Brow + k0);
    *(uint4*)(&Bl[ar * 40 + aj]) = *(const uint4*)(Brow + K + k0);
    __syncthreads();
    bf16x8 afh = *(const bf16x8*)(&Ah[(wave * 16 + l15) * 40 + quad * 8]);
    bf16x8 afl = *(const bf16x8*)(&Al[(wave * 16 + l15) * 40 + quad * 8]);
#pragma unroll
    for (int c = 0; c < 4; ++c) {
      bf16x8 bfh = *(const bf16x8*)(&Bh[(c * 16 + l15) * 40 + quad * 8]);
      bf16x8 bfl = *(const bf16x8*)(&Bl[(c * 16 + l15) * 40 + quad * 8]);
      acc[c] = __builtin_amdgcn_mfma_f32_16x16x32_bf16(afh, bfh, acc[c], 0, 0, 0);
      acc[c] = __builtin_amdgcn_mfma_f32_16x16x32_bf16(afh, bfl, acc[c], 0, 0, 0);
      acc[c] = __builtin_amdgcn_mfma_f32_16x16x32_bf16(afl, bfh, acc[c], 0, 0, 0);
    }
    __syncthreads();
  }
#pragma unroll
  for (int c = 0; c < 4; ++c)
#pragma unroll
    for (int rg = 0; rg < 4; ++rg) {
      int rowi = bm + wave * 16 + quad * 4 + rg;
      int coli = bn + c * 16 + l15;
      C[(size_t)rowi * N + coli] = acc[c][rg];
    }
}

// ---------------- GEMM3: 32x128 tile (N==128), grid (1, M/32); fused s1/s2 epilogue ----------------
// 4 waves: rhalf = w>>1 (16 rows), chalf = w&1 (64 cols, 4 frags).
__global__ __launch_bounds__(256) void k_gemm3(const u16* __restrict__ A, const u16* __restrict__ Bt,
    float* __restrict__ C, int K,
    const float* __restrict__ aptr, float* __restrict__ s1, float* __restrict__ s2) {
  __shared__ u16 Ah[32 * 40], Al[32 * 40];     // 2.6 KB each
  __shared__ u16 Bh[128 * 40], Bl[128 * 40];   // 10.2 KB each
  __shared__ float sp1[2][32], sp2[2][32];
  int tid = threadIdx.x;
  int bm = blockIdx.y * 32;
  int wave = tid >> 6, lane = tid & 63, l15 = lane & 15, quad = lane >> 4;
  int rhalf = wave >> 1, chalf = wave & 1;
  f32x4 acc[4] = {};
  int t7 = tid & 127;
  int ar = t7 >> 2, aj = (t7 & 3) << 3;        // 32 rows x 32 u16: tid<128 -> Ah, tid>=128 -> Al
  int br = tid >> 1, bj = (tid & 1) << 4;      // 128 rows x 32 u16: 2 uint4 per thread each buf
  const u16* Arow = A + (size_t)(bm + ar) * (2 * K) + aj + (tid < 128 ? 0 : K);
  u16* Adst = (tid < 128 ? Ah : Al) + ar * 40 + aj;
  const u16* Brow = Bt + (size_t)br * (2 * K) + bj;
  for (int k0 = 0; k0 < K; k0 += 32) {
    *(uint4*)Adst = *(const uint4*)(Arow + k0);
#pragma unroll
    for (int jj = 0; jj < 2; ++jj) {
      *(uint4*)(&Bh[br * 40 + bj + jj * 8]) = *(const uint4*)(Brow + k0 + jj * 8);
      *(uint4*)(&Bl[br * 40 + bj + jj * 8]) = *(const uint4*)(Brow + K + k0 + jj * 8);
    }
    __syncthreads();
    bf16x8 afh = *(const bf16x8*)(&Ah[(rhalf * 16 + l15) * 40 + quad * 8]);
    bf16x8 afl = *(const bf16x8*)(&Al[(rhalf * 16 + l15) * 40 + quad * 8]);
#pragma unroll
    for (int c = 0; c < 4; ++c) {
      bf16x8 bfh = *(const bf16x8*)(&Bh[(chalf * 64 + c * 16 + l15) * 40 + quad * 8]);
      bf16x8 bfl = *(const bf16x8*)(&Bl[(chalf * 64 + c * 16 + l15) * 40 + quad * 8]);
      acc[c] = __builtin_amdgcn_mfma_f32_16x16x32_bf16(afh, bfh, acc[c], 0, 0, 0);
      acc[c] = __builtin_amdgcn_mfma_f32_16x16x32_bf16(afh, bfl, acc[c], 0, 0, 0);
      acc[c] = __builtin_amdgcn_mfma_f32_16x16x32_bf16(afl, bfh, acc[c], 0, 0, 0);
    }
    __syncthreads();
  }
  // C write: row = bm + rhalf*16 + quad*4 + rg; col = chalf*64 + c*16 + l15
#pragma unroll
  for (int c = 0; c < 4; ++c)
#pragma unroll
    for (int rg = 0; rg < 4; ++rg) {
      int rowi = bm + rhalf * 16 + quad * 4 + rg;
      int coli = chalf * 64 + c * 16 + l15;
      C[(size_t)rowi * 128 + coli] = acc[c][rg];
    }
  // fused s1/s2: per-wave partial dot over its 64 cols, LDS-combine the two col-halves
  float a1v[4], a2v[4];
#pragma unroll
  for (int c = 0; c < 4; ++c) {
    a1v[c] = aptr[chalf * 64 + c * 16 + l15];
    a2v[c] = aptr[128 + chalf * 64 + c * 16 + l15];
  }
#pragma unroll
  for (int rg = 0; rg < 4; ++rg) {
    float p1 = 0.f, p2 = 0.f;
#pragma unroll
    for (int c = 0; c < 4; ++c) { p1 = fmaf(acc[c][rg], a1v[c], p1); p2 = fmaf(acc[c][rg], a2v[c], p2); }
#pragma unroll
    for (int m = 1; m < 16; m <<= 1) { p1 += __shfl_xor(p1, m); p2 += __shfl_xor(p2, m); }
    if (l15 == 0) {
      int rloc = rhalf * 16 + quad * 4 + rg;
      sp1[chalf][rloc] = p1; sp2[chalf][rloc] = p2;
    }
  }
  __syncthreads();
  if (tid < 32) {
    s1[bm + tid] = sp1[0][tid] + sp1[1][tid];
    s2[bm + tid] = sp2[0][tid] + sp2[1][tid];
  }
}

// ---------------- SpMM + bias + leaky + 2K-split-pack ----------------
__global__ __launch_bounds__(256) void k_spmm_pack(const float* __restrict__ Hin,
    const float* __restrict__ bias, const int* __restrict__ cnt,
    const int* __restrict__ cols, const float* __restrict__ vals, u16* __restrict__ Ap) {
  int i = blockIdx.x, t = threadIdx.x;
  int t64 = t & 63, g = t >> 6;
  __shared__ int sc[CAP];
  __shared__ float sv[CAP];
  __shared__ float4 sacc[4][64];
  int n = cnt[i];
  if (t < n) { sc[t] = cols[i * CAP + t]; sv[t] = vals[i * CAP + t]; }
  __syncthreads();
  float4 acc = {0.f, 0.f, 0.f, 0.f};
  const float4* H4 = (const float4*)Hin;
  for (int k = g; k < n; k += 4) {
    float w = sv[k];
    float4 v = H4[(size_t)sc[k] * 64 + t64];
    acc.x = fmaf(w, v.x, acc.x); acc.y = fmaf(w, v.y, acc.y);
    acc.z = fmaf(w, v.z, acc.z); acc.w = fmaf(w, v.w, acc.w);
  }
  sacc[g][t64] = acc;
  __syncthreads();
  if (t < 64) {
    float4 a0 = sacc[0][t], a1 = sacc[1][t], a2 = sacc[2][t], a3 = sacc[3][t];
    float4 bv = ((const float4*)bias)[t];
    float r[4] = { leaky_f(a0.x + a1.x + a2.x + a3.x + bv.x),
                   leaky_f(a0.y + a1.y + a2.y + a3.y + bv.y),
                   leaky_f(a0.z + a1.z + a2.z + a3.z + bv.z),
                   leaky_f(a0.w + a1.w + a2.w + a3.w + bv.w) };
    u16x4 hi4, lo4;
#pragma unroll
    for (int e = 0; e < 4; ++e) { u16 hh, ll; split_bf16(r[e], hh, ll); hi4[e] = hh; lo4[e] = ll; }
    size_t ro = (size_t)i * 512;                 // row = [hi(256) | lo(256)]
    *(u16x4*)(Ap + ro + 4 * t) = hi4;
    *(u16x4*)(Ap + ro + 256 + 4 * t) = lo4;
  }
}

// ---------------- attention: neighbor softmax + aggregate + leaky + mu/logvar split ----------------
__global__ __launch_bounds__(128) void k_attn(const float* __restrict__ h,
    const float* __restrict__ s1, const float* __restrict__ s2,
    const int* __restrict__ cnt, const int* __restrict__ cols, float* __restrict__ out) {
  int i = blockIdx.x, t = threadIdx.x;
  int t32 = t & 31, g = t >> 5;
  __shared__ int sc[CAP];
  __shared__ float sw[CAP];
  __shared__ float sred[2];
  __shared__ float4 sacc[4][32];
  int n = cnt[i];
  float s1i = s1[i];
  if (t < n) { int c = cols[i * CAP + t]; sc[t] = c; sw[t] = leaky_f(s1i + s2[c]); }
  __syncthreads();
  if (t < 64) {
    float m = -1e30f;
    if (t < n) m = sw[t];
    if (t + 64 < n) m = fmaxf(m, sw[t + 64]);
    for (int o = 32; o > 0; o >>= 1) m = fmaxf(m, __shfl_down(m, o));
    if (t == 0) sred[0] = m;
  }
  __syncthreads();
  float mx = sred[0];
  if (t < n) sw[t] = expf(sw[t] - mx);
  __syncthreads();
  if (t < 64) {
    float s = 0.f;
    if (t < n) s = sw[t];
    if (t + 64 < n) s += sw[t + 64];
    for (int o = 32; o > 0; o >>= 1) s += __shfl_down(s, o);
    if (t == 0) sred[1] = s;
  }
  __syncthreads();
  float inv = (n > 0) ? 1.0f / sred[1] : 0.f;
  float4 acc = {0.f, 0.f, 0.f, 0.f};
  const float4* h4 = (const float4*)h;
  for (int k = g; k < n; k += 4) {
    float w = sw[k];
    float4 v = h4[(size_t)sc[k] * 32 + t32];
    acc.x = fmaf(w, v.x, acc.x); acc.y = fmaf(w, v.y, acc.y);
    acc.z = fmaf(w, v.z, acc.z); acc.w = fmaf(w, v.w, acc.w);
  }
  sacc[g][t32] = acc;
  __syncthreads();
  if (t < 32) {
    float4 a0 = sacc[0][t], a1 = sacc[1][t], a2 = sacc[2][t], a3 = sacc[3][t];
    float4 r;
    r.x = leaky_f((a0.x + a1.x + a2.x + a3.x) * inv);
    r.y = leaky_f((a0.y + a1.y + a2.y + a3.y) * inv);
    r.z = leaky_f((a0.z + a1.z + a2.z + a3.z) * inv);
    r.w = leaky_f((a0.w + a1.w + a2.w + a3.w) * inv);
    float4* o4 = (float4*)out;
    if (t < 16) o4[(size_t)i * 16 + t] = r;                               // mu
    else        o4[(size_t)NROW * 16 + (size_t)i * 16 + (t - 16)] = r;    // logvar
  }
}

extern "C" void kernel_launch(void* const* d_in, const int* in_sizes, int n_in,
                              void* d_out, int out_size, void* d_ws, size_t ws_size,
                              hipStream_t stream) {
  const float* x   = (const float*)d_in[0];
  const float* adj = (const float*)d_in[1];
  const float* W1  = (const float*)d_in[2];
  const float* b1  = (const float*)d_in[3];
  const float* W2  = (const float*)d_in[4];
  const float* b2  = (const float*)d_in[5];
  const float* Wg  = (const float*)d_in[6];
  const float* a   = (const float*)d_in[7];
  float* out = (float*)d_out;

  char* ws = (char*)d_ws;
  int*   row_cnt  = (int*)  (ws + 0);          //  32 KB
  int*   row_cols = (int*)  (ws + 32768);      //   4 MB
  float* row_vals = (float*)(ws + 4227072);    //   4 MB
  u16*   B1t      = (u16*)  (ws + 8421376);    // 512 KB (256 x 1024)
  u16*   B2t      = (u16*)  (ws + 8945664);    // 256 KB (256 x 512)
  u16*   B3t      = (u16*)  (ws + 9207808);    // 128 KB (128 x 512)
  float* s1       = (float*)(ws + 9338880);    //  32 KB
  float* s2       = (float*)(ws + 9371648);    //  32 KB
  float* h        = (float*)(ws + 9404416);    //   4 MB (8192 x 128)
  float* H0T2     = (float*)(ws + 13598720);   //   8 MB (8192 x 256)
  u16*   Apack    = (u16*)  (ws + 21987328);   //   8 MB (8192 x 512), x1/x2 packed

  // 1. CSR build (268 MB adj read — structural floor) + weight pack, one dispatch
  k_csr_packw<<<NROW + 896, 256, 0, stream>>>(adj, row_cnt, row_cols, row_vals,
                                              W1, B1t, W2, B2t, Wg, B3t);
  // 2. H0 = x @ W1  (K=512) — 64x64 tiles, 512 blocks = 2/CU
  k_gemm_x<<<dim3(4, 128), 256, 0, stream>>>(x, B1t, H0T2, D_HID, D_IN);
  // 3. x1 = leaky(adj @ H0 + b1) -> packed
  k_spmm_pack<<<NROW, 256, 0, stream>>>(H0T2, b1, row_cnt, row_cols, row_vals, Apack);
  // 4. T2 = x1 @ W2  (K=256) — 64x64 tiles, 512 blocks
  k_gemm<<<dim3(4, 128), 256, 0, stream>>>(Apack, B2t, H0T2, D_HID, D_HID);
  // 5. x2 = leaky(adj @ T2 + b2) -> packed
  k_spmm_pack<<<NROW, 256, 0, stream>>>(H0T2, b2, row_cnt, row_cols, row_vals, Apack);
  // 6. h = x2 @ Wg (K=256, N=128) — 32x128 tiles, 256 blocks, fused s1/s2
  k_gemm3<<<dim3(1, 256), 256, 0, stream>>>(Apack, B3t, h, D_HID, a, s1, s2);
  // 7. masked softmax attention + aggregate + output split
  k_attn<<<NROW, 128, 0, stream>>>(h, s1, s2, row_cnt, row_cols, out);
}

// Round 7
// 471.928 us; speedup vs baseline: 1.1178x; 1.0476x over previous
//
#include <hip/hip_runtime.h>

typedef unsigned short u16;
typedef u16 u16x4 __attribute__((ext_vector_type(4)));
typedef __bf16 bf16x8 __attribute__((ext_vector_type(8)));
typedef float f32x4 __attribute__((ext_vector_type(4)));

#define NROW 8192
#define CAP 128
#define D_IN 512
#define D_HID 256
#define D_OUT 128

__device__ __forceinline__ float leaky_f(float x) { return x > 0.f ? x : 0.25f * x; }

__device__ __forceinline__ u16 f2bf_rne(float f) {
  unsigned u = __float_as_uint(f);
  u += 0x7fffu + ((u >> 16) & 1u);
  return (u16)(u >> 16);
}
__device__ __forceinline__ float bf2f(u16 v) { return __uint_as_float(((unsigned)v) << 16); }
__device__ __forceinline__ void split_bf16(float f, u16& hi, u16& lo) {
  hi = f2bf_rne(f);
  float fh = __uint_as_float(((unsigned)hi) << 16);
  lo = f2bf_rne(f - fh);
}

// ---------------- weight pack: W1/W2/Wg -> [hi(K)|lo(K)] transposed rows ----------------
__global__ __launch_bounds__(256) void k_packw(
    const float* __restrict__ W1, u16* __restrict__ B1,
    const float* __restrict__ W2, u16* __restrict__ B2,
    const float* __restrict__ Wg, u16* __restrict__ B3) {
  const float* W; u16* Bt; int K, Nc, id;
  int pb = blockIdx.x;                     // 896 blocks: 512 | 256 | 128
  if (pb < 512)      { W = W1; Bt = B1; K = D_IN;  Nc = D_HID; id = pb * 256 + threadIdx.x; }
  else if (pb < 768) { W = W2; Bt = B2; K = D_HID; Nc = D_HID; id = (pb - 512) * 256 + threadIdx.x; }
  else               { W = Wg; Bt = B3; K = D_HID; Nc = D_OUT; id = (pb - 768) * 256 + threadIdx.x; }
  int n = id % Nc, k = id / Nc;
  float f = W[id];
  u16 hi, lo; split_bf16(f, hi, lo);
  size_t ro = (size_t)n * 2 * K;
  Bt[ro + k] = hi; Bt[ro + K + k] = lo;
}

// ---------------- merged dispatch: blocks [0,512) = GEMM1 (x @ W1), blocks [512,8704) = CSR ----------------
// Independent work: GEMM1 overlaps with the 268 MB HBM-bound adj scan instead of serializing after it.
__global__ __launch_bounds__(256) void k_csr_gemm1(const float* __restrict__ adj,
    int* __restrict__ cnt, int* __restrict__ cols, float* __restrict__ vals,
    const float* __restrict__ X, const u16* __restrict__ Bt, float* __restrict__ C) {
  __shared__ u16 Ah[64 * 40], Al[64 * 40];
  __shared__ u16 Bh[64 * 40], Bl[64 * 40];   // 20.5 KB
  __shared__ int csrc;
  int b = blockIdx.x;
  int tid = threadIdx.x;
  if (b < 512) {  // ---- GEMM1: 64x64 tile, in-register fp32->split-bf16 of x; K=512, N=256 ----
    const int N = D_HID, K = D_IN;
    int bm = (b >> 2) * 64, bn = (b & 3) * 64;
    int wave = tid >> 6, lane = tid & 63, l15 = lane & 15, quad = lane >> 4;
    f32x4 acc[4] = {};
    int ar = tid >> 2, aj = (tid & 3) << 3;
    const float* Xrow = X + (size_t)(bm + ar) * K + aj;
    const u16* Brow = Bt + (size_t)(bn + ar) * (2 * K) + aj;
    for (int k0 = 0; k0 < K; k0 += 32) {
      alignas(16) u16 hh[8], ll[8];
      float xv[8];
      *(float4*)(xv)     = *(const float4*)(Xrow + k0);
      *(float4*)(xv + 4) = *(const float4*)(Xrow + k0 + 4);
#pragma unroll
      for (int e = 0; e < 8; ++e) split_bf16(xv[e], hh[e], ll[e]);
      *(uint4*)(&Ah[ar * 40 + aj]) = *(const uint4*)hh;
      *(uint4*)(&Al[ar * 40 + aj]) = *(const uint4*)ll;
      *(uint4*)(&Bh[ar * 40 + aj]) = *(const uint4*)(Brow + k0);
      *(uint4*)(&Bl[ar * 40 + aj]) = *(const uint4*)(Brow + K + k0);
      __syncthreads();
      bf16x8 afh = *(const bf16x8*)(&Ah[(wave * 16 + l15) * 40 + quad * 8]);
      bf16x8 afl = *(const bf16x8*)(&Al[(wave * 16 + l15) * 40 + quad * 8]);
#pragma unroll
      for (int c = 0; c < 4; ++c) {
        bf16x8 bfh = *(const bf16x8*)(&Bh[(c * 16 + l15) * 40 + quad * 8]);
        bf16x8 bfl = *(const bf16x8*)(&Bl[(c * 16 + l15) * 40 + quad * 8]);
        acc[c] = __builtin_amdgcn_mfma_f32_16x16x32_bf16(afh, bfh, acc[c], 0, 0, 0);
        acc[c] = __builtin_amdgcn_mfma_f32_16x16x32_bf16(afh, bfl, acc[c], 0, 0, 0);
        acc[c] = __builtin_amdgcn_mfma_f32_16x16x32_bf16(afl, bfh, acc[c], 0, 0, 0);
      }
      __syncthreads();
    }
#pragma unroll
    for (int c = 0; c < 4; ++c)
#pragma unroll
      for (int rg = 0; rg < 4; ++rg) {
        int rowi = bm + wave * 16 + quad * 4 + rg;   // C/D: col=lane&15, row=quad*4+reg
        int coli = bn + c * 16 + l15;
        C[(size_t)rowi * N + coli] = acc[c][rg];
      }
    return;
  }
  // ---- CSR row build ----
  int i = b - 512;
  if (tid == 0) csrc = 0;
  __syncthreads();
  const float4* row = (const float4*)(adj + (size_t)i * NROW);
  for (int j4 = tid; j4 < NROW / 4; j4 += 256) {
    float4 v = row[j4];
    int base = j4 * 4;
    if (v.x > 0.f) { int s = atomicAdd(&csrc, 1); if (s < CAP) { cols[i*CAP+s] = base;   vals[i*CAP+s] = v.x; } }
    if (v.y > 0.f) { int s = atomicAdd(&csrc, 1); if (s < CAP) { cols[i*CAP+s] = base+1; vals[i*CAP+s] = v.y; } }
    if (v.z > 0.f) { int s = atomicAdd(&csrc, 1); if (s < CAP) { cols[i*CAP+s] = base+2; vals[i*CAP+s] = v.z; } }
    if (v.w > 0.f) { int s = atomicAdd(&csrc, 1); if (s < CAP) { cols[i*CAP+s] = base+3; vals[i*CAP+s] = v.w; } }
  }
  __syncthreads();
  if (tid == 0) cnt[i] = (csrc < CAP) ? csrc : CAP;
}

// ---------------- GEMM2: 64x64 tile, packed A; grid (N/64, M/64) ----------------
__global__ __launch_bounds__(256) void k_gemm(const u16* __restrict__ A, const u16* __restrict__ Bt,
    float* __restrict__ C, int N, int K) {
  __shared__ u16 Ah[64 * 40], Al[64 * 40];
  __shared__ u16 Bh[64 * 40], Bl[64 * 40];
  int tid = threadIdx.x;
  int bm = blockIdx.y * 64, bn = blockIdx.x * 64;
  int wave = tid >> 6, lane = tid & 63, l15 = lane & 15, quad = lane >> 4;
  f32x4 acc[4] = {};
  int ar = tid >> 2, aj = (tid & 3) << 3;
  const u16* Arow = A + (size_t)(bm + ar) * (2 * K) + aj;
  const u16* Brow = Bt + (size_t)(bn + ar) * (2 * K) + aj;
  for (int k0 = 0; k0 < K; k0 += 32) {
    *(uint4*)(&Ah[ar * 40 + aj]) = *(const uint4*)(Arow + k0);
    *(uint4*)(&Al[ar * 40 + aj]) = *(const uint4*)(Arow + K + k0);
    *(uint4*)(&Bh[ar * 40 + aj]) = *(const uint4*)(Brow + k0);
    *(uint4*)(&Bl[ar * 40 + aj]) = *(const uint4*)(Brow + K + k0);
    __syncthreads();
    bf16x8 afh = *(const bf16x8*)(&Ah[(wave * 16 + l15) * 40 + quad * 8]);
    bf16x8 afl = *(const bf16x8*)(&Al[(wave * 16 + l15) * 40 + quad * 8]);
#pragma unroll
    for (int c = 0; c < 4; ++c) {
      bf16x8 bfh = *(const bf16x8*)(&Bh[(c * 16 + l15) * 40 + quad * 8]);
      bf16x8 bfl = *(const bf16x8*)(&Bl[(c * 16 + l15) * 40 + quad * 8]);
      acc[c] = __builtin_amdgcn_mfma_f32_16x16x32_bf16(afh, bfh, acc[c], 0, 0, 0);
      acc[c] = __builtin_amdgcn_mfma_f32_16x16x32_bf16(afh, bfl, acc[c], 0, 0, 0);
      acc[c] = __builtin_amdgcn_mfma_f32_16x16x32_bf16(afl, bfh, acc[c], 0, 0, 0);
    }
    __syncthreads();
  }
#pragma unroll
  for (int c = 0; c < 4; ++c)
#pragma unroll
    for (int rg = 0; rg < 4; ++rg) {
      int rowi = bm + wave * 16 + quad * 4 + rg;
      int coli = bn + c * 16 + l15;
      C[(size_t)rowi * N + coli] = acc[c][rg];
    }
}

// ---------------- GEMM3: 32x128 tile (N==128); h out in bf16; fused s1/s2 (fp32-exact) ----------------
__global__ __launch_bounds__(256) void k_gemm3(const u16* __restrict__ A, const u16* __restrict__ Bt,
    u16* __restrict__ Hb, int K,
    const float* __restrict__ aptr, float* __restrict__ s1, float* __restrict__ s2) {
  __shared__ u16 Ah[32 * 40], Al[32 * 40];
  __shared__ u16 Bh[128 * 40], Bl[128 * 40];
  __shared__ float sp1[2][32], sp2[2][32];
  int tid = threadIdx.x;
  int bm = blockIdx.y * 32;
  int wave = tid >> 6, lane = tid & 63, l15 = lane & 15, quad = lane >> 4;
  int rhalf = wave >> 1, chalf = wave & 1;
  f32x4 acc[4] = {};
  int t7 = tid & 127;
  int ar = t7 >> 2, aj = (t7 & 3) << 3;
  int br = tid >> 1, bj = (tid & 1) << 4;
  const u16* Arow = A + (size_t)(bm + ar) * (2 * K) + aj + (tid < 128 ? 0 : K);
  u16* Adst = (tid < 128 ? Ah : Al) + ar * 40 + aj;
  const u16* Brow = Bt + (size_t)br * (2 * K) + bj;
  for (int k0 = 0; k0 < K; k0 += 32) {
    *(uint4*)Adst = *(const uint4*)(Arow + k0);
#pragma unroll
    for (int jj = 0; jj < 2; ++jj) {
      *(uint4*)(&Bh[br * 40 + bj + jj * 8]) = *(const uint4*)(Brow + k0 + jj * 8);
      *(uint4*)(&Bl[br * 40 + bj + jj * 8]) = *(const uint4*)(Brow + K + k0 + jj * 8);
    }
    __syncthreads();
    bf16x8 afh = *(const bf16x8*)(&Ah[(rhalf * 16 + l15) * 40 + quad * 8]);
    bf16x8 afl = *(const bf16x8*)(&Al[(rhalf * 16 + l15) * 40 + quad * 8]);
#pragma unroll
    for (int c = 0; c < 4; ++c) {
      bf16x8 bfh = *(const bf16x8*)(&Bh[(chalf * 64 + c * 16 + l15) * 40 + quad * 8]);
      bf16x8 bfl = *(const bf16x8*)(&Bl[(chalf * 64 + c * 16 + l15) * 40 + quad * 8]);
      acc[c] = __builtin_amdgcn_mfma_f32_16x16x32_bf16(afh, bfh, acc[c], 0, 0, 0);
      acc[c] = __builtin_amdgcn_mfma_f32_16x16x32_bf16(afh, bfl, acc[c], 0, 0, 0);
      acc[c] = __builtin_amdgcn_mfma_f32_16x16x32_bf16(afl, bfh, acc[c], 0, 0, 0);
    }
    __syncthreads();
  }
  // h write (bf16, only the att@h aggregation consumes it; logits below stay fp32)
#pragma unroll
  for (int c = 0; c < 4; ++c)
#pragma unroll
    for (int rg = 0; rg < 4; ++rg) {
      int rowi = bm + rhalf * 16 + quad * 4 + rg;
      int coli = chalf * 64 + c * 16 + l15;
      Hb[(size_t)rowi * 128 + coli] = f2bf_rne(acc[c][rg]);
    }
  // fused s1/s2 from fp32 accumulators (exact logit path)
  float a1v[4], a2v[4];
#pragma unroll
  for (int c = 0; c < 4; ++c) {
    a1v[c] = aptr[chalf * 64 + c * 16 + l15];
    a2v[c] = aptr[128 + chalf * 64 + c * 16 + l15];
  }
#pragma unroll
  for (int rg = 0; rg < 4; ++rg) {
    float p1 = 0.f, p2 = 0.f;
#pragma unroll
    for (int c = 0; c < 4; ++c) { p1 = fmaf(acc[c][rg], a1v[c], p1); p2 = fmaf(acc[c][rg], a2v[c], p2); }
#pragma unroll
    for (int m = 1; m < 16; m <<= 1) { p1 += __shfl_xor(p1, m); p2 += __shfl_xor(p2, m); }
    if (l15 == 0) {
      int rloc = rhalf * 16 + quad * 4 + rg;
      sp1[chalf][rloc] = p1; sp2[chalf][rloc] = p2;
    }
  }
  __syncthreads();
  if (tid < 32) {
    s1[bm + tid] = sp1[0][tid] + sp1[1][tid];
    s2[bm + tid] = sp2[0][tid] + sp2[1][tid];
  }
}

// ---------------- SpMM + bias + leaky + 2K-split-pack (fp32 H input — exact) ----------------
__global__ __launch_bounds__(256) void k_spmm_pack(const float* __restrict__ Hin,
    const float* __restrict__ bias, const int* __restrict__ cnt,
    const int* __restrict__ cols, const float* __restrict__ vals, u16* __restrict__ Ap) {
  int i = blockIdx.x, t = threadIdx.x;
  int t64 = t & 63, g = t >> 6;
  __shared__ int sc[CAP];
  __shared__ float sv[CAP];
  __shared__ float4 sacc[4][64];
  int n = cnt[i];
  if (t < n) { sc[t] = cols[i * CAP + t]; sv[t] = vals[i * CAP + t]; }
  __syncthreads();
  float4 acc = {0.f, 0.f, 0.f, 0.f};
  const float4* H4 = (const float4*)Hin;
  for (int k = g; k < n; k += 4) {
    float w = sv[k];
    float4 v = H4[(size_t)sc[k] * 64 + t64];
    acc.x = fmaf(w, v.x, acc.x); acc.y = fmaf(w, v.y, acc.y);
    acc.z = fmaf(w, v.z, acc.z); acc.w = fmaf(w, v.w, acc.w);
  }
  sacc[g][t64] = acc;
  __syncthreads();
  if (t < 64) {
    float4 a0 = sacc[0][t], a1 = sacc[1][t], a2 = sacc[2][t], a3 = sacc[3][t];
    float4 bv = ((const float4*)bias)[t];
    float r[4] = { leaky_f(a0.x + a1.x + a2.x + a3.x + bv.x),
                   leaky_f(a0.y + a1.y + a2.y + a3.y + bv.y),
                   leaky_f(a0.z + a1.z + a2.z + a3.z + bv.z),
                   leaky_f(a0.w + a1.w + a2.w + a3.w + bv.w) };
    u16x4 hi4, lo4;
#pragma unroll
    for (int e = 0; e < 4; ++e) { u16 hh, ll; split_bf16(r[e], hh, ll); hi4[e] = hh; lo4[e] = ll; }
    size_t ro = (size_t)i * 512;
    *(u16x4*)(Ap + ro + 4 * t) = hi4;
    *(u16x4*)(Ap + ro + 256 + 4 * t) = lo4;
  }
}

// ---------------- attention: fp32 logits, bf16 h gather, mu/logvar split ----------------
__global__ __launch_bounds__(128) void k_attn(const u16* __restrict__ Hb,
    const float* __restrict__ s1, const float* __restrict__ s2,
    const int* __restrict__ cnt, const int* __restrict__ cols, float* __restrict__ out) {
  int i = blockIdx.x, t = threadIdx.x;
  int t32 = t & 31, g = t >> 5;
  __shared__ int sc[CAP];
  __shared__ float sw[CAP];
  __shared__ float sred[2];
  __shared__ float4 sacc[4][32];
  int n = cnt[i];
  float s1i = s1[i];
  if (t < n) { int c = cols[i * CAP + t]; sc[t] = c; sw[t] = leaky_f(s1i + s2[c]); }
  __syncthreads();
  if (t < 64) {
    float m = -1e30f;
    if (t < n) m = sw[t];
    if (t + 64 < n) m = fmaxf(m, sw[t + 64]);
    for (int o = 32; o > 0; o >>= 1) m = fmaxf(m, __shfl_down(m, o));
    if (t == 0) sred[0] = m;
  }
  __syncthreads();
  float mx = sred[0];
  if (t < n) sw[t] = expf(sw[t] - mx);
  __syncthreads();
  if (t < 64) {
    float s = 0.f;
    if (t < n) s = sw[t];
    if (t + 64 < n) s += sw[t + 64];
    for (int o = 32; o > 0; o >>= 1) s += __shfl_down(s, o);
    if (t == 0) sred[1] = s;
  }
  __syncthreads();
  float inv = (n > 0) ? 1.0f / sred[1] : 0.f;
  float4 acc = {0.f, 0.f, 0.f, 0.f};
  for (int k = g; k < n; k += 4) {
    float w = sw[k];
    u16x4 v = *(const u16x4*)(Hb + (size_t)sc[k] * 128 + 4 * t32);
    acc.x = fmaf(w, bf2f(v[0]), acc.x); acc.y = fmaf(w, bf2f(v[1]), acc.y);
    acc.z = fmaf(w, bf2f(v[2]), acc.z); acc.w = fmaf(w, bf2f(v[3]), acc.w);
  }
  sacc[g][t32] = acc;
  __syncthreads();
  if (t < 32) {
    float4 a0 = sacc[0][t], a1 = sacc[1][t], a2 = sacc[2][t], a3 = sacc[3][t];
    float4 r;
    r.x = leaky_f((a0.x + a1.x + a2.x + a3.x) * inv);
    r.y = leaky_f((a0.y + a1.y + a2.y + a3.y) * inv);
    r.z = leaky_f((a0.z + a1.z + a2.z + a3.z) * inv);
    r.w = leaky_f((a0.w + a1.w + a2.w + a3.w) * inv);
    float4* o4 = (float4*)out;
    if (t < 16) o4[(size_t)i * 16 + t] = r;                               // mu
    else        o4[(size_t)NROW * 16 + (size_t)i * 16 + (t - 16)] = r;    // logvar
  }
}

extern "C" void kernel_launch(void* const* d_in, const int* in_sizes, int n_in,
                              void* d_out, int out_size, void* d_ws, size_t ws_size,
                              hipStream_t stream) {
  const float* x   = (const float*)d_in[0];
  const float* adj = (const float*)d_in[1];
  const float* W1  = (const float*)d_in[2];
  const float* b1  = (const float*)d_in[3];
  const float* W2  = (const float*)d_in[4];
  const float* b2  = (const float*)d_in[5];
  const float* Wg  = (const float*)d_in[6];
  const float* a   = (const float*)d_in[7];
  float* out = (float*)d_out;

  char* ws = (char*)d_ws;
  int*   row_cnt  = (int*)  (ws + 0);          //  32 KB
  int*   row_cols = (int*)  (ws + 32768);      //   4 MB
  float* row_vals = (float*)(ws + 4227072);    //   4 MB
  u16*   B1t      = (u16*)  (ws + 8421376);    // 512 KB (256 x 1024)
  u16*   B2t      = (u16*)  (ws + 8945664);    // 256 KB (256 x 512)
  u16*   B3t      = (u16*)  (ws + 9207808);    // 128 KB (128 x 512)
  float* s1       = (float*)(ws + 9338880);    //  32 KB
  float* s2       = (float*)(ws + 9371648);    //  32 KB
  u16*   hbf      = (u16*)  (ws + 9404416);    //   2 MB (8192 x 128 bf16)
  float* H0T2     = (float*)(ws + 13598720);   //   8 MB (8192 x 256 fp32)
  u16*   Apack    = (u16*)  (ws + 21987328);   //   8 MB (8192 x 512), x1/x2 packed

  // 1. weight pack (tiny; must precede gemm1)
  k_packw<<<896, 256, 0, stream>>>(W1, B1t, W2, B2t, Wg, B3t);
  // 2. merged: GEMM1 (512 blocks, compute) + CSR build (8192 blocks, HBM) — independent, overlap
  k_csr_gemm1<<<512 + NROW, 256, 0, stream>>>(adj, row_cnt, row_cols, row_vals, x, B1t, H0T2);
  // 3. x1 = leaky(adj @ H0 + b1) -> packed
  k_spmm_pack<<<NROW, 256, 0, stream>>>(H0T2, b1, row_cnt, row_cols, row_vals, Apack);
  // 4. T2 = x1 @ W2  (K=256)
  k_gemm<<<dim3(4, 128), 256, 0, stream>>>(Apack, B2t, H0T2, D_HID, D_HID);
  // 5. x2 = leaky(adj @ T2 + b2) -> packed
  k_spmm_pack<<<NROW, 256, 0, stream>>>(H0T2, b2, row_cnt, row_cols, row_vals, Apack);
  // 6. h (bf16) = x2 @ Wg + fused fp32 s1/s2
  k_gemm3<<<dim3(1, 256), 256, 0, stream>>>(Apack, B3t, hbf, D_HID, a, s1, s2);
  // 7. masked softmax attention (fp32 logits) + bf16 aggregate + output split
  k_attn<<<NROW, 128, 0, stream>>>(hbf, s1, s2, row_cnt, row_cols, out);
}